// Round 2
// baseline (265.580 us; speedup 1.0000x reference)
//
#include <hip/hip_runtime.h>

using v8h = __attribute__((ext_vector_type(8))) _Float16;       // 8 f16 MFMA frag
using v4f = __attribute__((ext_vector_type(4))) float;          // MFMA acc
using v4u = __attribute__((ext_vector_type(4))) unsigned short; // 8B packed
using v8u = __attribute__((ext_vector_type(8))) unsigned short; // 16B copy

// fp32 <-> fp16
__device__ __forceinline__ unsigned short f2h(float x) {
  _Float16 h = (_Float16)x;
  return __builtin_bit_cast(unsigned short, h);
}
__device__ __forceinline__ float h2f(unsigned short u) {
  return (float)__builtin_bit_cast(_Float16, u);
}

// async global -> LDS, 16 bytes per lane (global_load_lds_dwordx4)
__device__ __forceinline__ void gl_lds16(const unsigned short* g, unsigned short* l) {
  __builtin_amdgcn_global_load_lds(
      (const __attribute__((address_space(1))) unsigned int*)g,
      (__attribute__((address_space(3))) unsigned int*)l, 16, 0, 0);
}

// ---------------------------------------------------------------------------
// f32 -> f16 bulk convert, 8 elems/thread
// ---------------------------------------------------------------------------
__global__ void cvt_kernel(const float* __restrict__ src,
                           unsigned short* __restrict__ dst, int n8) {
  int i = blockIdx.x * 256 + threadIdx.x;
  if (i >= n8) return;
  const float* p = src + (size_t)i * 8;
  float4 a = *(const float4*)p;
  float4 b = *(const float4*)(p + 4);
  v8u o = {f2h(a.x), f2h(a.y), f2h(a.z), f2h(a.w),
           f2h(b.x), f2h(b.y), f2h(b.z), f2h(b.w)};
  *(v8u*)(dst + (size_t)i * 8) = o;
}

// ---------------------------------------------------------------------------
// QKV projection: 256x256 tile, BK=64, 512 thr = 8 waves (2M x 4N),
// 8-phase counted-vmcnt schedule (T3+T4) + LDS XOR swizzle (T2) + setprio (T5).
// A[8192][768] f16, Bw[2304][768] f16 (row = out-feature), C = A.Bw^T.
// cols < 1536 -> QK f16 (ldc 1536); cols >= 1536 -> VT transposed f16.
// Grid (9, 32). LDS 128KB = 2 dbuf x (A 256x64 + B 256x64) f16.
//
// Half-tiles: Ah0 = A rows 0-127, Ah1 = rows 128-255; Bh0/Bh1 same for B.
// Per-tile consumption (all waves): B LDS reads done after ph2-end barrier,
// A LDS reads done after ph3-end barrier. Stage plan per tile t (buf b=t&1):
//   ph1: Ah1(t+1) -> buf b^1   (no reader of b^1 during tile t)
//   ph3: Bh0(t+2) -> buf b     (B free since ph2-end)
//   ph4: Bh1(t+2), Ah0(t+2)    (A free since ph3-end)
//   Ah1(t+2) staged at tile t+1 ph1.
// vmcnt(6) at ph4 leaves exactly [Bh0,Bh1,Ah0](t+2) in flight (2 loads/half),
// guaranteeing tile t+1 fully landed; barrier makes that cross-wave.
// ---------------------------------------------------------------------------
__global__ __launch_bounds__(512, 2)
void qkv8_kernel(const unsigned short* __restrict__ A,
                 const unsigned short* __restrict__ Bw,
                 unsigned short* __restrict__ QK,
                 unsigned short* __restrict__ VT) {
  __shared__ unsigned short sm[65536];  // 128 KB
  const int t    = (int)threadIdx.x;
  const int ln   = t & 63;
  const int wv   = t >> 6;
  const int quad = ln >> 4;
  const int L    = ln & 15;
  const int wm   = wv >> 2;   // 0..1 -> 128-row half of the 256-row tile
  const int wn   = wv & 3;    // 0..3 -> 64-col stripe
  const long m0  = (long)blockIdx.y * 256;
  const long n0  = (long)blockIdx.x * 256;

  // Staging geometry: thread t stages 16B at LDS linear slot t (phys slot t&7
  // of row t>>3 within a 64-row unit). Pre-swizzled GLOBAL source so that
  // phys slot p of row r holds logical k-slot p ^ (r&7).
  const int srow = t >> 3;                        // 0..63
  const int scol = ((t & 7) ^ (srow & 7)) * 8;    // shorts
  const unsigned short* Ath = A + (m0 + srow) * 768 + scol;
  const unsigned short* Bth = Bw + (n0 + srow) * 768 + scol;
  unsigned short* lth = &sm[t * 8];

  // Read geometry: logical slot (ks*4+quad) lives at phys slot ^(row&7);
  // row&7 == L&7 for every fragment row (all other terms are multiples of 8).
  const int l7   = L & 7;
  const int sl0  = ((0 + quad) ^ l7) * 8;   // ks=0, shorts
  const int sl1  = ((4 + quad) ^ l7) * 8;   // ks=1
  const int arow = (wm * 128 + L) * 64;     // shorts; +mq*4096, +i*1024
  const int brow = (wn * 64 + L) * 64;      // shorts; +nh*2048, +j*1024

  v4f acc[8][4];
#pragma unroll
  for (int i = 0; i < 8; i++)
#pragma unroll
    for (int j = 0; j < 4; j++) acc[i][j] = (v4f){0.f, 0.f, 0.f, 0.f};

  // stage one 128-row half-tile = 2 x gl_lds16 per thread (2 vmcnt ticks)
  auto stA = [&](int tile, int h) {
    if (tile >= 12) return;
    const unsigned short* g = Ath + (h * 128) * 768 + tile * 64;
    unsigned short* l = lth + (tile & 1) * 32768 + h * 8192;
    gl_lds16(g, l);                    // rows h*128 + 0..63
    gl_lds16(g + 64 * 768, l + 4096);  // rows h*128 + 64..127
  };
  auto stB = [&](int tile, int h) {
    if (tile >= 12) return;
    const unsigned short* g = Bth + (h * 128) * 768 + tile * 64;
    unsigned short* l = lth + (tile & 1) * 32768 + 16384 + h * 8192;
    gl_lds16(g, l);
    gl_lds16(g + 64 * 768, l + 4096);
  };

  // prologue: tile0 complete + 3 half-tiles of tile1 in flight (6 ticks)
  stB(0, 0); stB(0, 1); stA(0, 0); stA(0, 1);
  stB(1, 0); stB(1, 1); stA(1, 0);
  asm volatile("s_waitcnt vmcnt(6)" ::: "memory");
  __builtin_amdgcn_s_barrier();
  __builtin_amdgcn_sched_barrier(0);

#pragma unroll 2
  for (int kt = 0; kt < 12; ++kt) {
    const unsigned short* sA = &sm[(kt & 1) * 32768];
    const unsigned short* sB = sA + 16384;
    v8h af[4][2], b0[2][2], b1[2][2];

    // ---- phase 1: quadrant (mq0, nh0) — 12 ds_read_b128 + 1 half stage
#pragma unroll
    for (int i = 0; i < 4; i++) {
      af[i][0] = *(const v8h*)&sA[arow + i * 1024 + sl0];
      af[i][1] = *(const v8h*)&sA[arow + i * 1024 + sl1];
    }
#pragma unroll
    for (int j = 0; j < 2; j++) {
      b0[j][0] = *(const v8h*)&sB[brow + j * 1024 + sl0];
      b0[j][1] = *(const v8h*)&sB[brow + j * 1024 + sl1];
    }
    stA(kt + 1, 1);
    __builtin_amdgcn_s_barrier();
    asm volatile("s_waitcnt lgkmcnt(0)" ::: "memory");
    __builtin_amdgcn_sched_barrier(0);
    __builtin_amdgcn_s_setprio(1);
#pragma unroll
    for (int i = 0; i < 4; i++)
#pragma unroll
      for (int j = 0; j < 2; j++) {
        acc[i][j] = __builtin_amdgcn_mfma_f32_16x16x32_f16(af[i][0], b0[j][0], acc[i][j], 0, 0, 0);
        acc[i][j] = __builtin_amdgcn_mfma_f32_16x16x32_f16(af[i][1], b0[j][1], acc[i][j], 0, 0, 0);
      }
    __builtin_amdgcn_s_setprio(0);
    __builtin_amdgcn_s_barrier();
    __builtin_amdgcn_sched_barrier(0);

    // ---- phase 2: (mq0, nh1) — 4 ds_read_b128
#pragma unroll
    for (int j = 0; j < 2; j++) {
      b1[j][0] = *(const v8h*)&sB[brow + 2048 + j * 1024 + sl0];
      b1[j][1] = *(const v8h*)&sB[brow + 2048 + j * 1024 + sl1];
    }
    __builtin_amdgcn_s_barrier();
    asm volatile("s_waitcnt lgkmcnt(0)" ::: "memory");
    __builtin_amdgcn_sched_barrier(0);
    __builtin_amdgcn_s_setprio(1);
#pragma unroll
    for (int i = 0; i < 4; i++)
#pragma unroll
      for (int j = 0; j < 2; j++) {
        acc[i][2 + j] = __builtin_amdgcn_mfma_f32_16x16x32_f16(af[i][0], b1[j][0], acc[i][2 + j], 0, 0, 0);
        acc[i][2 + j] = __builtin_amdgcn_mfma_f32_16x16x32_f16(af[i][1], b1[j][1], acc[i][2 + j], 0, 0, 0);
      }
    __builtin_amdgcn_s_setprio(0);
    __builtin_amdgcn_s_barrier();
    __builtin_amdgcn_sched_barrier(0);

    // ---- phase 3: (mq1, nh1) — 8 ds_read_b128 + 1 half stage
#pragma unroll
    for (int i = 0; i < 4; i++) {
      af[i][0] = *(const v8h*)&sA[arow + 4096 + i * 1024 + sl0];
      af[i][1] = *(const v8h*)&sA[arow + 4096 + i * 1024 + sl1];
    }
    stB(kt + 2, 0);
    __builtin_amdgcn_s_barrier();
    asm volatile("s_waitcnt lgkmcnt(0)" ::: "memory");
    __builtin_amdgcn_sched_barrier(0);
    __builtin_amdgcn_s_setprio(1);
#pragma unroll
    for (int i = 0; i < 4; i++)
#pragma unroll
      for (int j = 0; j < 2; j++) {
        acc[4 + i][2 + j] = __builtin_amdgcn_mfma_f32_16x16x32_f16(af[i][0], b1[j][0], acc[4 + i][2 + j], 0, 0, 0);
        acc[4 + i][2 + j] = __builtin_amdgcn_mfma_f32_16x16x32_f16(af[i][1], b1[j][1], acc[4 + i][2 + j], 0, 0, 0);
      }
    __builtin_amdgcn_s_setprio(0);
    __builtin_amdgcn_s_barrier();
    __builtin_amdgcn_sched_barrier(0);

    // ---- phase 4: (mq1, nh0) — reuses af (ph3) and b0 (ph1); 2 half stages
    stB(kt + 2, 1);
    stA(kt + 2, 0);
    __builtin_amdgcn_s_barrier();
    __builtin_amdgcn_sched_barrier(0);
    __builtin_amdgcn_s_setprio(1);
#pragma unroll
    for (int i = 0; i < 4; i++)
#pragma unroll
      for (int j = 0; j < 2; j++) {
        acc[4 + i][j] = __builtin_amdgcn_mfma_f32_16x16x32_f16(af[i][0], b0[j][0], acc[4 + i][j], 0, 0, 0);
        acc[4 + i][j] = __builtin_amdgcn_mfma_f32_16x16x32_f16(af[i][1], b0[j][1], acc[4 + i][j], 0, 0, 0);
      }
    __builtin_amdgcn_s_setprio(0);
    // counted tile-boundary wait: tile kt+1 fully landed, [Bh0,Bh1,Ah0](kt+2)
    // (6 loads) stay in flight across the barrier. Tail drains to 0.
    if (kt + 2 < 12)      { asm volatile("s_waitcnt vmcnt(6)" ::: "memory"); }
    else if (kt + 1 < 12) { asm volatile("s_waitcnt vmcnt(0)" ::: "memory"); }
    __builtin_amdgcn_s_barrier();
    __builtin_amdgcn_sched_barrier(0);
  }

  // epilogue: C/D frag mapping col = L, row = quad*4 + r
  if (n0 < 1536) {
#pragma unroll
    for (int mi = 0; mi < 8; mi++) {
      const long row = m0 + wm * 128 + (mi >> 2) * 64 + (mi & 3) * 16 + quad * 4;
#pragma unroll
      for (int nj = 0; nj < 4; nj++) {
        const long col = n0 + wn * 64 + nj * 16 + L;
#pragma unroll
        for (int r = 0; r < 4; r++)
          QK[(row + r) * 1536 + col] = f2h(acc[mi][nj][r]);
      }
    }
  } else {
#pragma unroll
    for (int mi = 0; mi < 8; mi++) {
      const long token = m0 + wm * 128 + (mi >> 2) * 64 + (mi & 3) * 16 + quad * 4;
      const int b  = (int)(token >> 11);
      const int tk = (int)(token & 2047);
#pragma unroll
      for (int nj = 0; nj < 4; nj++) {
        const int colp = (int)(n0 + wn * 64 + nj * 16 + L) - 1536;
        const int h = colp >> 8;
        const int d = colp & 255;
        v4u val = {f2h(acc[mi][nj][0]), f2h(acc[mi][nj][1]),
                   f2h(acc[mi][nj][2]), f2h(acc[mi][nj][3])};
        *(v4u*)(&VT[((long)(b * 3 + h) * 256 + d) * 2048 + tk]) = val;
      }
    }
  }
}

// ---------------------------------------------------------------------------
// f16 GEMM, m97 recipe (kept for the output projection): C[m,n] =
// sum_k A[m,k]*Bw[n,k], 128x128 tile, BK=32. MODE 0: plain store (f32 if OF).
// ---------------------------------------------------------------------------
template <int MODE, bool OF>
__global__ __launch_bounds__(256, 2)
void gemm_async_kernel(const unsigned short* __restrict__ A,
                       const unsigned short* __restrict__ Bw,
                       void* __restrict__ Cv, unsigned short* __restrict__ VT,
                       int K, int ldc) {
  __shared__ unsigned short As[4096];
  __shared__ unsigned short Bs[4096];

  const int t    = threadIdx.x;
  const int ln   = t & 63;
  const int wv   = t >> 6;
  const int quad = ln >> 4;
  const int L    = ln & 15;
  const int wm   = (wv >> 1) * 64;
  const int wn   = (wv & 1) * 64;
  const long m0  = (long)blockIdx.y * 128;
  const long n0  = (long)blockIdx.x * 128;

  v4f acc[4][4];
#pragma unroll
  for (int i = 0; i < 4; i++)
#pragma unroll
    for (int j = 0; j < 4; j++) acc[i][j] = (v4f){0.f, 0.f, 0.f, 0.f};

  const int ar = t >> 2;
  const int ac = (t & 3) * 8;
  const unsigned short* Ag = A + (m0 + ar) * (long)K + ac;
  const unsigned short* Bg = Bw + (n0 + ar) * (long)K + ac;
  unsigned short* la = &As[t * 8];
  unsigned short* lb = &Bs[t * 8];
  const long rowskip = 64L * K;

  for (int k0 = 0; k0 < K; k0 += 32) {
    gl_lds16(Ag + k0, la);
    gl_lds16(Ag + rowskip + k0, la + 2048);
    gl_lds16(Bg + k0, lb);
    gl_lds16(Bg + rowskip + k0, lb + 2048);
    __syncthreads();

    v8h af[4], bfr[4];
#pragma unroll
    for (int i = 0; i < 4; i++)
      af[i] = *(const v8h*)(&As[(wm + i * 16 + L) * 32 + quad * 8]);
#pragma unroll
    for (int j = 0; j < 4; j++)
      bfr[j] = *(const v8h*)(&Bs[(wn + j * 16 + L) * 32 + quad * 8]);
#pragma unroll
    for (int i = 0; i < 4; i++)
#pragma unroll
      for (int j = 0; j < 4; j++)
        acc[i][j] = __builtin_amdgcn_mfma_f32_16x16x32_f16(af[i], bfr[j], acc[i][j], 0, 0, 0);
    __syncthreads();
  }

  if (MODE == 0 || n0 < 1536) {
#pragma unroll
    for (int i = 0; i < 4; i++)
#pragma unroll
      for (int j = 0; j < 4; j++)
#pragma unroll
        for (int r = 0; r < 4; r++) {
          long row = m0 + wm + i * 16 + quad * 4 + r;
          long col = n0 + wn + j * 16 + L;
          if (OF) ((float*)Cv)[row * ldc + col] = acc[i][j][r];
          else    ((unsigned short*)Cv)[row * ldc + col] = f2h(acc[i][j][r]);
        }
  } else {
#pragma unroll
    for (int i = 0; i < 4; i++)
#pragma unroll
      for (int j = 0; j < 4; j++) {
        int colp   = (int)(n0 + wn + j * 16 + L) - 1536;
        int h      = colp >> 8;
        int d      = colp & 255;
        long token = m0 + wm + i * 16 + quad * 4;
        int b  = (int)(token >> 11);
        int tk = (int)(token & 2047);
        v4u val = {f2h(acc[i][j][0]), f2h(acc[i][j][1]), f2h(acc[i][j][2]), f2h(acc[i][j][3])};
        *(v4u*)(&VT[((long)(b * 3 + h) * 256 + d) * 2048 + tk]) = val;
      }
  }
}

// ---------------------------------------------------------------------------
// Score GEMM: S_tile(i,j)[128][128] = Q_block_i . K_block_j^T (raw, unscaled).
// Packed lower-tri storage: slot = bh*136 + i(i+1)/2 + j. Grid (136, 12).
// ---------------------------------------------------------------------------
__global__ __launch_bounds__(256, 2)
void gemm_sc_kernel(const unsigned short* __restrict__ QK,
                    unsigned short* __restrict__ Sc) {
  __shared__ unsigned short As[4096];
  __shared__ unsigned short Bs[4096];

  const int t    = threadIdx.x;
  const int ln   = t & 63;
  const int wv   = t >> 6;
  const int quad = ln >> 4;
  const int L    = ln & 15;
  const int wm   = (wv >> 1) * 64;
  const int wn   = (wv & 1) * 64;

  int x = (int)blockIdx.x, i = 0;
  while (x >= i + 1) { x -= i + 1; i++; }
  const int j  = x;
  const int bh = (int)blockIdx.y;
  const int b  = bh / 3, h = bh % 3;
  const long tokA = (long)b * 2048 + i * 128;
  const long tokB = (long)b * 2048 + j * 128;

  v4f acc[4][4];
#pragma unroll
  for (int ii = 0; ii < 4; ii++)
#pragma unroll
    for (int jj = 0; jj < 4; jj++) acc[ii][jj] = (v4f){0.f, 0.f, 0.f, 0.f};

  const int ar = t >> 2;
  const int ac = (t & 3) * 8;
  const unsigned short* Ag = QK + (tokA + ar) * 1536 + h * 256 + ac;
  const unsigned short* Bg = QK + (tokB + ar) * 1536 + 768 + h * 256 + ac;
  unsigned short* la = &As[t * 8];
  unsigned short* lb = &Bs[t * 8];
  const long rowskip = 64L * 1536;

  for (int k0 = 0; k0 < 256; k0 += 32) {
    gl_lds16(Ag + k0, la);
    gl_lds16(Ag + rowskip + k0, la + 2048);
    gl_lds16(Bg + k0, lb);
    gl_lds16(Bg + rowskip + k0, lb + 2048);
    __syncthreads();

    v8h af[4], bfr[4];
#pragma unroll
    for (int ii = 0; ii < 4; ii++)
      af[ii] = *(const v8h*)(&As[(wm + ii * 16 + L) * 32 + quad * 8]);
#pragma unroll
    for (int jj = 0; jj < 4; jj++)
      bfr[jj] = *(const v8h*)(&Bs[(wn + jj * 16 + L) * 32 + quad * 8]);
#pragma unroll
    for (int ii = 0; ii < 4; ii++)
#pragma unroll
      for (int jj = 0; jj < 4; jj++)
        acc[ii][jj] = __builtin_amdgcn_mfma_f32_16x16x32_f16(af[ii], bfr[jj], acc[ii][jj], 0, 0, 0);
    __syncthreads();
  }

  unsigned short* Sb = Sc + ((long)bh * 136 + blockIdx.x) * 16384;
#pragma unroll
  for (int ii = 0; ii < 4; ii++)
#pragma unroll
    for (int jj = 0; jj < 4; jj++)
#pragma unroll
      for (int r = 0; r < 4; r++) {
        int row = wm + ii * 16 + quad * 4 + r;
        int col = wn + jj * 16 + L;
        Sb[row * 128 + col] = f2h(acc[ii][jj][r]);
      }
}

// ---------------------------------------------------------------------------
// Softmax, one WAVE per q-row; whole row cached in registers (<=32 f32/lane).
// Single global read + single write. Block = 4 waves; grid (512, 12).
// Heavy rows (large i) dispatched first. Masked cols written as exact 0.
// ---------------------------------------------------------------------------
__global__ __launch_bounds__(256, 4)
void softmax_kernel(unsigned short* __restrict__ Sc) {
  const int tt   = threadIdx.x;
  const int wv   = tt >> 6;
  const int lane = tt & 63;
  const int bh   = (int)blockIdx.y;

  const int r = 2047 - ((int)blockIdx.x * 4 + wv);  // heavy rows first
  const int i = r >> 7;
  const int rowloc = r & 127;
  const long base = ((long)bh * 136 + (long)i * (i + 1) / 2) * 16384 + rowloc * 128;
  const int Lrow = (i + 1) * 128;
  const int nch = (i + 4) >> 2;  // ceil((i+1)/4) chunks of 512 cols

  float xs[4][8];
  float mx = -1e30f;
  for (int k = 0; k < nch; k++) {
    int c0 = k * 512 + lane * 8;
    if (c0 < Lrow) {
      int j = c0 >> 7;
      v8u v = *(const v8u*)(Sc + base + (long)j * 16384 + (c0 & 127));
#pragma unroll
      for (int e = 0; e < 8; e++) {
        float f = (c0 + e <= r) ? h2f(v[e]) * 0.0625f : -1e30f;
        xs[k][e] = f;
        mx = fmaxf(mx, f);
      }
    } else {
#pragma unroll
      for (int e = 0; e < 8; e++) xs[k][e] = -1e30f;
    }
  }
#pragma unroll
  for (int d = 1; d < 64; d <<= 1) mx = fmaxf(mx, __shfl_xor(mx, d));

  float sum = 0.f;
  for (int k = 0; k < nch; k++)
#pragma unroll
    for (int e = 0; e < 8; e++) {
      float ex = __expf(xs[k][e] - mx);  // masked: exp(-huge) = 0
      xs[k][e] = ex;
      sum += ex;
    }
#pragma unroll
  for (int d = 1; d < 64; d <<= 1) sum += __shfl_xor(sum, d);
  const float inv = 1.0f / sum;

  for (int k = 0; k < nch; k++) {
    int c0 = k * 512 + lane * 8;
    if (c0 < Lrow) {
      int j = c0 >> 7;
      v8u o;
#pragma unroll
      for (int e = 0; e < 8; e++) o[e] = f2h(xs[k][e] * inv);
      *(v8u*)(Sc + base + (long)j * 16384 + (c0 & 127)) = o;
    }
  }
}

// ---------------------------------------------------------------------------
// PV GEMM, j-parity split: partial(i,nh,par) = sum_{j==par (mod 2), j<=i}
// P(i,j).V_j, written f16 to Pp. Grid x: 64 = (16 i heavy-first)x(2 nh)x(2 par).
// ---------------------------------------------------------------------------
__global__ __launch_bounds__(256, 2)
void gemm_pv_kernel(const unsigned short* __restrict__ Sc,
                    const unsigned short* __restrict__ VT,
                    unsigned short* __restrict__ Pp) {
  __shared__ unsigned short As[4096];
  __shared__ unsigned short Bs[4096];

  const int t    = threadIdx.x;
  const int ln   = t & 63;
  const int wv   = t >> 6;
  const int quad = ln >> 4;
  const int L    = ln & 15;
  const int wm   = (wv >> 1) * 64;
  const int wn   = (wv & 1) * 64;

  const int ix  = (int)blockIdx.x;
  const int i   = 15 - (ix >> 2);  // heavy first
  const int nh  = (ix >> 1) & 1;
  const int par = ix & 1;
  const int bh  = (int)blockIdx.y;

  v4f acc[4][4];
#pragma unroll
  for (int ii = 0; ii < 4; ii++)
#pragma unroll
    for (int jj = 0; jj < 4; jj++) acc[ii][jj] = (v4f){0.f, 0.f, 0.f, 0.f};

  const int ar = t >> 2;
  const int ac = (t & 3) * 8;
  const unsigned short* Abase =
      Sc + ((long)bh * 136 + (long)i * (i + 1) / 2) * 16384 + ar * 128 + ac;
  const unsigned short* Bg =
      VT + ((long)bh * 256 + nh * 128 + ar) * 2048 + ac;
  unsigned short* la = &As[t * 8];
  unsigned short* lb = &Bs[t * 8];

  for (int j = par; j <= i; j += 2) {
    const unsigned short* Aj = Abase + (long)j * 16384;
    const unsigned short* Bj = Bg + j * 128;
#pragma unroll
    for (int k0 = 0; k0 < 128; k0 += 32) {
      gl_lds16(Aj + k0, la);
      gl_lds16(Aj + 64 * 128 + k0, la + 2048);
      gl_lds16(Bj + k0, lb);
      gl_lds16(Bj + 64 * 2048 + k0, lb + 2048);
      __syncthreads();

      v8h af[4], bfr[4];
#pragma unroll
      for (int ii = 0; ii < 4; ii++)
        af[ii] = *(const v8h*)(&As[(wm + ii * 16 + L) * 32 + quad * 8]);
#pragma unroll
      for (int jj = 0; jj < 4; jj++)
        bfr[jj] = *(const v8h*)(&Bs[(wn + jj * 16 + L) * 32 + quad * 8]);
#pragma unroll
      for (int ii = 0; ii < 4; ii++)
#pragma unroll
        for (int jj = 0; jj < 4; jj++)
          acc[ii][jj] = __builtin_amdgcn_mfma_f32_16x16x32_f16(af[ii], bfr[jj], acc[ii][jj], 0, 0, 0);
      __syncthreads();
    }
  }

  unsigned short* Pb = Pp + ((((long)bh * 16 + i) * 2 + nh) * 2 + par) * 16384;
#pragma unroll
  for (int ii = 0; ii < 4; ii++)
#pragma unroll
    for (int jj = 0; jj < 4; jj++)
#pragma unroll
      for (int r = 0; r < 4; r++) {
        int row = wm + ii * 16 + quad * 4 + r;
        int col = wn + jj * 16 + L;
        Pb[row * 128 + col] = f2h(acc[ii][jj][r]);
      }
}

// ---------------------------------------------------------------------------
// Combine the two parity partials -> AO. Grid (32 = 16i x 2nh, 12).
// Thread: row = tid>>1, 64-col half (tid&1). 8 x v8u.
// ---------------------------------------------------------------------------
__global__ __launch_bounds__(256, 4)
void pv_combine_kernel(const unsigned short* __restrict__ Pp,
                       unsigned short* __restrict__ AO) {
  const int i  = (int)blockIdx.x >> 1;
  const int nh = (int)blockIdx.x & 1;
  const int bh = (int)blockIdx.y;
  const int b  = bh / 3, h = bh % 3;

  const int tid = threadIdx.x;
  const int row = tid >> 1;
  const int cs  = (tid & 1) * 64;

  const unsigned short* P0 = Pp + ((((long)bh * 16 + i) * 2 + nh) * 2 + 0) * 16384 + row * 128 + cs;
  const unsigned short* P1 = P0 + 16384;
  unsigned short* Or = AO + ((long)b * 2048 + i * 128 + row) * 768 + h * 256 + nh * 128 + cs;
#pragma unroll
  for (int q = 0; q < 8; q++) {
    v8u a = *(const v8u*)(P0 + q * 8);
    v8u c = *(const v8u*)(P1 + q * 8);
    v8u o;
#pragma unroll
    for (int e = 0; e < 8; e++) o[e] = f2h(h2f(a[e]) + h2f(c[e]));
    *(v8u*)(Or + q * 8) = o;
  }
}

// ---------------------------------------------------------------------------
extern "C" void kernel_launch(void* const* d_in, const int* in_sizes, int n_in,
                              void* d_out, int out_size, void* d_ws, size_t ws_size,
                              hipStream_t stream) {
  const float* X     = (const float*)d_in[0];  // [4,2048,768] f32
  const float* Wqkv  = (const float*)d_in[1];  // [2304,768]   f32
  const float* Wproj = (const float*)d_in[2];  // [768,768]    f32
  float* out = (float*)d_out;                  // [4,2048,768] f32

  const size_t SZ_QK = (size_t)8192 * 1536 * 2;       // 25.2 MB
  const size_t SZ_VT = (size_t)3072 * 2048 * 2;       // 12.6 MB
  const size_t SZ_SC = (size_t)12 * 136 * 16384 * 2;  // 53.5 MB
  const size_t SZ_AO = (size_t)8192 * 768 * 2;        // 12.6 MB
  const size_t SZ_WQ = (size_t)2304 * 768 * 2;        //  3.5 MB

  char* ws = (char*)d_ws;
  unsigned short* QKb = (unsigned short*)ws;
  unsigned short* Ppb = QKb;  // alias: QK dead after gemm_sc; Pp = 12*16*2*2*16384*2 B == SZ_QK
  unsigned short* VTb = (unsigned short*)(ws + SZ_QK);
  unsigned short* Scb = (unsigned short*)(ws + SZ_QK + SZ_VT);
  unsigned short* Xb  = Scb;  // alias: Xb dead before Sc written
  unsigned short* AOb = (unsigned short*)(ws + SZ_QK + SZ_VT + SZ_SC);
  unsigned short* Wqb = (unsigned short*)(ws + SZ_QK + SZ_VT + SZ_SC + SZ_AO);
  unsigned short* Wpb = (unsigned short*)(ws + SZ_QK + SZ_VT + SZ_SC + SZ_AO + SZ_WQ);

  dim3 blk(256, 1, 1);
  // 0) one-time f32 -> f16 conversions
  cvt_kernel<<<dim3(3072, 1, 1), blk, 0, stream>>>(X, Xb, 786432);
  cvt_kernel<<<dim3(864, 1, 1), blk, 0, stream>>>(Wqkv, Wqb, 221184);
  cvt_kernel<<<dim3(288, 1, 1), blk, 0, stream>>>(Wproj, Wpb, 73728);
  // 1) QKV projection (V stored transposed), 256^2 8-phase schedule
  qkv8_kernel<<<dim3(9, 32, 1), dim3(512, 1, 1), 0, stream>>>(Xb, Wqb, QKb, VTb);
  // 2) dense causal attention as GEMMs
  gemm_sc_kernel<<<dim3(136, 12, 1), blk, 0, stream>>>(QKb, Scb);
  softmax_kernel<<<dim3(512, 12, 1), blk, 0, stream>>>(Scb);
  gemm_pv_kernel<<<dim3(64, 12, 1), blk, 0, stream>>>(Scb, VTb, Ppb);
  pv_combine_kernel<<<dim3(32, 12, 1), blk, 0, stream>>>(Ppb, AOb);
  // 3) output projection, f32 store
  gemm_async_kernel<0, true><<<dim3(6, 64, 1), blk, 0, stream>>>(
      AOb, Wpb, out, (unsigned short*)nullptr, 768, 768);
}

// Round 3
// 257.126 us; speedup vs baseline: 1.0329x; 1.0329x over previous
//
#include <hip/hip_runtime.h>

using v8h = __attribute__((ext_vector_type(8))) _Float16;       // 8 f16 MFMA frag
using v4f = __attribute__((ext_vector_type(4))) float;          // MFMA acc
using v4u = __attribute__((ext_vector_type(4))) unsigned short; // 8B packed
using v8u = __attribute__((ext_vector_type(8))) unsigned short; // 16B copy

// fp32 <-> fp16
__device__ __forceinline__ unsigned short f2h(float x) {
  _Float16 h = (_Float16)x;
  return __builtin_bit_cast(unsigned short, h);
}
__device__ __forceinline__ float h2f(unsigned short u) {
  return (float)__builtin_bit_cast(_Float16, u);
}

// async global -> LDS, 16 bytes per lane (global_load_lds_dwordx4)
__device__ __forceinline__ void gl_lds16(const unsigned short* g, unsigned short* l) {
  __builtin_amdgcn_global_load_lds(
      (const __attribute__((address_space(1))) unsigned int*)g,
      (__attribute__((address_space(3))) unsigned int*)l, 16, 0, 0);
}

// ---------------------------------------------------------------------------
// All three f32 -> f16 conversions in ONE launch. Grid 4224 x 256, exact
// multiples (3072 / 864 / 288 blocks), 8 elems/thread, no guards needed.
// ---------------------------------------------------------------------------
__global__ void cvt3_kernel(const float* __restrict__ X,
                            const float* __restrict__ Wq,
                            const float* __restrict__ Wp,
                            unsigned short* __restrict__ Xb,
                            unsigned short* __restrict__ Wqb,
                            unsigned short* __restrict__ Wpb) {
  const int blk = (int)blockIdx.x;
  const float* src;
  unsigned short* dst;
  int i;
  if (blk < 3072)      { src = X;  dst = Xb;  i = blk * 256 + threadIdx.x; }
  else if (blk < 3936) { src = Wq; dst = Wqb; i = (blk - 3072) * 256 + threadIdx.x; }
  else                 { src = Wp; dst = Wpb; i = (blk - 3936) * 256 + threadIdx.x; }
  const float* p = src + (size_t)i * 8;
  float4 a = *(const float4*)p;
  float4 b = *(const float4*)(p + 4);
  v8u o = {f2h(a.x), f2h(a.y), f2h(a.z), f2h(a.w),
           f2h(b.x), f2h(b.y), f2h(b.z), f2h(b.w)};
  *(v8u*)(dst + (size_t)i * 8) = o;
}

// ---------------------------------------------------------------------------
// QK projection only (V moved into scv_kernel): 256x256 tile, BK=64,
// 512 thr = 8 waves (2M x 4N), 8-phase counted-vmcnt schedule + XOR swizzle
// + setprio. A[8192][768] f16, Bw rows 0..1535 (Q,K out-features).
// Grid (6, 32) = 192 blocks -> ONE round at 1 block/CU (128KB LDS).
// ---------------------------------------------------------------------------
__global__ __launch_bounds__(512, 2)
void qkv8_kernel(const unsigned short* __restrict__ A,
                 const unsigned short* __restrict__ Bw,
                 unsigned short* __restrict__ QK) {
  __shared__ unsigned short sm[65536];  // 128 KB
  const int t    = (int)threadIdx.x;
  const int ln   = t & 63;
  const int wv   = t >> 6;
  const int quad = ln >> 4;
  const int L    = ln & 15;
  const int wm   = wv >> 2;   // 0..1 -> 128-row half of the 256-row tile
  const int wn   = wv & 3;    // 0..3 -> 64-col stripe
  const long m0  = (long)blockIdx.y * 256;
  const long n0  = (long)blockIdx.x * 256;

  // Staging: thread t stages 16B at LDS linear slot t; pre-swizzled GLOBAL
  // source so phys slot p of row r holds logical k-slot p ^ (r&7).
  const int srow = t >> 3;                        // 0..63
  const int scol = ((t & 7) ^ (srow & 7)) * 8;    // shorts
  const unsigned short* Ath = A + (m0 + srow) * 768 + scol;
  const unsigned short* Bth = Bw + (n0 + srow) * 768 + scol;
  unsigned short* lth = &sm[t * 8];

  // Read: logical slot (ks*4+quad) lives at phys slot ^(row&7); row&7 == L&7.
  const int l7   = L & 7;
  const int sl0  = ((0 + quad) ^ l7) * 8;   // ks=0, shorts
  const int sl1  = ((4 + quad) ^ l7) * 8;   // ks=1
  const int arow = (wm * 128 + L) * 64;     // shorts; +mq*4096, +i*1024
  const int brow = (wn * 64 + L) * 64;      // shorts; +nh*2048, +j*1024

  v4f acc[8][4];
#pragma unroll
  for (int i = 0; i < 8; i++)
#pragma unroll
    for (int j = 0; j < 4; j++) acc[i][j] = (v4f){0.f, 0.f, 0.f, 0.f};

  auto stA = [&](int tile, int h) {
    if (tile >= 12) return;
    const unsigned short* g = Ath + (h * 128) * 768 + tile * 64;
    unsigned short* l = lth + (tile & 1) * 32768 + h * 8192;
    gl_lds16(g, l);
    gl_lds16(g + 64 * 768, l + 4096);
  };
  auto stB = [&](int tile, int h) {
    if (tile >= 12) return;
    const unsigned short* g = Bth + (h * 128) * 768 + tile * 64;
    unsigned short* l = lth + (tile & 1) * 32768 + 16384 + h * 8192;
    gl_lds16(g, l);
    gl_lds16(g + 64 * 768, l + 4096);
  };

  // prologue: tile0 complete + 3 half-tiles of tile1 in flight (6 ticks)
  stB(0, 0); stB(0, 1); stA(0, 0); stA(0, 1);
  stB(1, 0); stB(1, 1); stA(1, 0);
  asm volatile("s_waitcnt vmcnt(6)" ::: "memory");
  __builtin_amdgcn_s_barrier();
  __builtin_amdgcn_sched_barrier(0);

#pragma unroll 2
  for (int kt = 0; kt < 12; ++kt) {
    const unsigned short* sA = &sm[(kt & 1) * 32768];
    const unsigned short* sB = sA + 16384;
    v8h af[4][2], b0[2][2], b1[2][2];

    // ---- phase 1: quadrant (mq0, nh0) — 12 ds_read_b128 + 1 half stage
#pragma unroll
    for (int i = 0; i < 4; i++) {
      af[i][0] = *(const v8h*)&sA[arow + i * 1024 + sl0];
      af[i][1] = *(const v8h*)&sA[arow + i * 1024 + sl1];
    }
#pragma unroll
    for (int j = 0; j < 2; j++) {
      b0[j][0] = *(const v8h*)&sB[brow + j * 1024 + sl0];
      b0[j][1] = *(const v8h*)&sB[brow + j * 1024 + sl1];
    }
    stA(kt + 1, 1);
    __builtin_amdgcn_s_barrier();
    asm volatile("s_waitcnt lgkmcnt(0)" ::: "memory");
    __builtin_amdgcn_sched_barrier(0);
    __builtin_amdgcn_s_setprio(1);
#pragma unroll
    for (int i = 0; i < 4; i++)
#pragma unroll
      for (int j = 0; j < 2; j++) {
        acc[i][j] = __builtin_amdgcn_mfma_f32_16x16x32_f16(af[i][0], b0[j][0], acc[i][j], 0, 0, 0);
        acc[i][j] = __builtin_amdgcn_mfma_f32_16x16x32_f16(af[i][1], b0[j][1], acc[i][j], 0, 0, 0);
      }
    __builtin_amdgcn_s_setprio(0);
    __builtin_amdgcn_s_barrier();
    __builtin_amdgcn_sched_barrier(0);

    // ---- phase 2: (mq0, nh1) — 4 ds_read_b128
#pragma unroll
    for (int j = 0; j < 2; j++) {
      b1[j][0] = *(const v8h*)&sB[brow + 2048 + j * 1024 + sl0];
      b1[j][1] = *(const v8h*)&sB[brow + 2048 + j * 1024 + sl1];
    }
    __builtin_amdgcn_s_barrier();
    asm volatile("s_waitcnt lgkmcnt(0)" ::: "memory");
    __builtin_amdgcn_sched_barrier(0);
    __builtin_amdgcn_s_setprio(1);
#pragma unroll
    for (int i = 0; i < 4; i++)
#pragma unroll
      for (int j = 0; j < 2; j++) {
        acc[i][2 + j] = __builtin_amdgcn_mfma_f32_16x16x32_f16(af[i][0], b1[j][0], acc[i][2 + j], 0, 0, 0);
        acc[i][2 + j] = __builtin_amdgcn_mfma_f32_16x16x32_f16(af[i][1], b1[j][1], acc[i][2 + j], 0, 0, 0);
      }
    __builtin_amdgcn_s_setprio(0);
    __builtin_amdgcn_s_barrier();
    __builtin_amdgcn_sched_barrier(0);

    // ---- phase 3: (mq1, nh1) — 8 ds_read_b128 + 1 half stage
#pragma unroll
    for (int i = 0; i < 4; i++) {
      af[i][0] = *(const v8h*)&sA[arow + 4096 + i * 1024 + sl0];
      af[i][1] = *(const v8h*)&sA[arow + 4096 + i * 1024 + sl1];
    }
    stB(kt + 2, 0);
    __builtin_amdgcn_s_barrier();
    asm volatile("s_waitcnt lgkmcnt(0)" ::: "memory");
    __builtin_amdgcn_sched_barrier(0);
    __builtin_amdgcn_s_setprio(1);
#pragma unroll
    for (int i = 0; i < 4; i++)
#pragma unroll
      for (int j = 0; j < 2; j++) {
        acc[4 + i][2 + j] = __builtin_amdgcn_mfma_f32_16x16x32_f16(af[i][0], b1[j][0], acc[4 + i][2 + j], 0, 0, 0);
        acc[4 + i][2 + j] = __builtin_amdgcn_mfma_f32_16x16x32_f16(af[i][1], b1[j][1], acc[4 + i][2 + j], 0, 0, 0);
      }
    __builtin_amdgcn_s_setprio(0);
    __builtin_amdgcn_s_barrier();
    __builtin_amdgcn_sched_barrier(0);

    // ---- phase 4: (mq1, nh0) — reuses af (ph3) and b0 (ph1); 2 half stages
    stB(kt + 2, 1);
    stA(kt + 2, 0);
    __builtin_amdgcn_s_barrier();
    __builtin_amdgcn_sched_barrier(0);
    __builtin_amdgcn_s_setprio(1);
#pragma unroll
    for (int i = 0; i < 4; i++)
#pragma unroll
      for (int j = 0; j < 2; j++) {
        acc[4 + i][j] = __builtin_amdgcn_mfma_f32_16x16x32_f16(af[i][0], b0[j][0], acc[4 + i][j], 0, 0, 0);
        acc[4 + i][j] = __builtin_amdgcn_mfma_f32_16x16x32_f16(af[i][1], b0[j][1], acc[4 + i][j], 0, 0, 0);
      }
    __builtin_amdgcn_s_setprio(0);
    if (kt + 2 < 12)      { asm volatile("s_waitcnt vmcnt(6)" ::: "memory"); }
    else if (kt + 1 < 12) { asm volatile("s_waitcnt vmcnt(0)" ::: "memory"); }
    __builtin_amdgcn_s_barrier();
    __builtin_amdgcn_sched_barrier(0);
  }

  // epilogue: C/D frag mapping col = L, row = quad*4 + r; all cols < 1536
#pragma unroll
  for (int mi = 0; mi < 8; mi++) {
    const long row = m0 + wm * 128 + (mi >> 2) * 64 + (mi & 3) * 16 + quad * 4;
#pragma unroll
    for (int nj = 0; nj < 4; nj++) {
      const long col = n0 + wn * 64 + nj * 16 + L;
#pragma unroll
      for (int r = 0; r < 4; r++)
        QK[(row + r) * 1536 + col] = f2h(acc[mi][nj][r]);
    }
  }
}

// ---------------------------------------------------------------------------
// f16 GEMM, m97 recipe (output projection): C[m,n] = sum_k A[m,k]*Bw[n,k],
// 128x128 tile, BK=32, f32 store.
// ---------------------------------------------------------------------------
__global__ __launch_bounds__(256, 2)
void gemm_proj_kernel(const unsigned short* __restrict__ A,
                      const unsigned short* __restrict__ Bw,
                      float* __restrict__ C) {
  __shared__ unsigned short As[4096];
  __shared__ unsigned short Bs[4096];

  const int t    = threadIdx.x;
  const int ln   = t & 63;
  const int wv   = t >> 6;
  const int quad = ln >> 4;
  const int L    = ln & 15;
  const int wm   = (wv >> 1) * 64;
  const int wn   = (wv & 1) * 64;
  const long m0  = (long)blockIdx.y * 128;
  const long n0  = (long)blockIdx.x * 128;

  v4f acc[4][4];
#pragma unroll
  for (int i = 0; i < 4; i++)
#pragma unroll
    for (int j = 0; j < 4; j++) acc[i][j] = (v4f){0.f, 0.f, 0.f, 0.f};

  const int ar = t >> 2;
  const int ac = (t & 3) * 8;
  const unsigned short* Ag = A + (m0 + ar) * 768 + ac;
  const unsigned short* Bg = Bw + (n0 + ar) * 768 + ac;
  unsigned short* la = &As[t * 8];
  unsigned short* lb = &Bs[t * 8];
  const long rowskip = 64L * 768;

  for (int k0 = 0; k0 < 768; k0 += 32) {
    gl_lds16(Ag + k0, la);
    gl_lds16(Ag + rowskip + k0, la + 2048);
    gl_lds16(Bg + k0, lb);
    gl_lds16(Bg + rowskip + k0, lb + 2048);
    __syncthreads();

    v8h af[4], bfr[4];
#pragma unroll
    for (int i = 0; i < 4; i++)
      af[i] = *(const v8h*)(&As[(wm + i * 16 + L) * 32 + quad * 8]);
#pragma unroll
    for (int j = 0; j < 4; j++)
      bfr[j] = *(const v8h*)(&Bs[(wn + j * 16 + L) * 32 + quad * 8]);
#pragma unroll
    for (int i = 0; i < 4; i++)
#pragma unroll
      for (int j = 0; j < 4; j++)
        acc[i][j] = __builtin_amdgcn_mfma_f32_16x16x32_f16(af[i], bfr[j], acc[i][j], 0, 0, 0);
    __syncthreads();
  }

#pragma unroll
  for (int i = 0; i < 4; i++)
#pragma unroll
    for (int j = 0; j < 4; j++)
#pragma unroll
      for (int r = 0; r < 4; r++) {
        long row = m0 + wm + i * 16 + quad * 4 + r;
        long col = n0 + wn + j * 16 + L;
        C[row * 768 + col] = acc[i][j][r];
      }
}

// ---------------------------------------------------------------------------
// COMBINED dispatch: score GEMM tiles + V-projection tiles (same 256-thread
// 128^2 m97 shape). Grid (168, 12):
//   x < 136 : S_tile(i,j) = Q_i . K_j^T  (packed lower-tri, slot bh*136+...)
//   x >= 136: V-projection 128^2 tile -> VT transposed. vi = (x-136) + 32*bh
//             in [0,384): mt = vi & 63 (M-tile of 8192), nt = vi >> 6 (of 6).
// ---------------------------------------------------------------------------
__global__ __launch_bounds__(256, 2)
void scv_kernel(const unsigned short* __restrict__ QK,
                const unsigned short* __restrict__ Xb,
                const unsigned short* __restrict__ Wq,
                unsigned short* __restrict__ Sc,
                unsigned short* __restrict__ VT) {
  __shared__ unsigned short As[4096];
  __shared__ unsigned short Bs[4096];

  const int t    = threadIdx.x;
  const int ln   = t & 63;
  const int wv   = t >> 6;
  const int quad = ln >> 4;
  const int L    = ln & 15;
  const int wm   = (wv >> 1) * 64;
  const int wn   = (wv & 1) * 64;
  const int ar   = t >> 2;
  const int ac   = (t & 3) * 8;

  const int x  = (int)blockIdx.x;
  const int bh = (int)blockIdx.y;
  const bool isV = (x >= 136);

  const unsigned short* Ag;
  const unsigned short* Bg;
  long rowstride;
  int Klen;
  int mt = 0, nt = 0;  // V-path tile coords

  if (!isV) {
    int xx = x, i = 0;
    while (xx >= i + 1) { xx -= i + 1; i++; }
    const int j = xx;
    const int b = bh / 3, h = bh % 3;
    const long tokA = (long)b * 2048 + i * 128;
    const long tokB = (long)b * 2048 + j * 128;
    Ag = QK + (tokA + ar) * 1536 + h * 256 + ac;
    Bg = QK + (tokB + ar) * 1536 + 768 + h * 256 + ac;
    rowstride = 1536;
    Klen = 256;
  } else {
    const int vi = (x - 136) + 32 * bh;  // 0..383
    mt = vi & 63;
    nt = vi >> 6;  // 0..5
    Ag = Xb + ((long)mt * 128 + ar) * 768 + ac;
    Bg = Wq + ((long)(1536 + nt * 128) + ar) * 768 + ac;
    rowstride = 768;
    Klen = 768;
  }

  v4f acc[4][4];
#pragma unroll
  for (int ii = 0; ii < 4; ii++)
#pragma unroll
    for (int jj = 0; jj < 4; jj++) acc[ii][jj] = (v4f){0.f, 0.f, 0.f, 0.f};

  unsigned short* la = &As[t * 8];
  unsigned short* lb = &Bs[t * 8];
  const long rowskip = 64L * rowstride;

  for (int k0 = 0; k0 < Klen; k0 += 32) {
    gl_lds16(Ag + k0, la);
    gl_lds16(Ag + rowskip + k0, la + 2048);
    gl_lds16(Bg + k0, lb);
    gl_lds16(Bg + rowskip + k0, lb + 2048);
    __syncthreads();

    v8h af[4], bfr[4];
#pragma unroll
    for (int ii = 0; ii < 4; ii++)
      af[ii] = *(const v8h*)(&As[(wm + ii * 16 + L) * 32 + quad * 8]);
#pragma unroll
    for (int jj = 0; jj < 4; jj++)
      bfr[jj] = *(const v8h*)(&Bs[(wn + jj * 16 + L) * 32 + quad * 8]);
#pragma unroll
    for (int ii = 0; ii < 4; ii++)
#pragma unroll
      for (int jj = 0; jj < 4; jj++)
        acc[ii][jj] = __builtin_amdgcn_mfma_f32_16x16x32_f16(af[ii], bfr[jj], acc[ii][jj], 0, 0, 0);
    __syncthreads();
  }

  if (!isV) {
    unsigned short* Sb = Sc + ((long)bh * 136 + x) * 16384;
#pragma unroll
    for (int ii = 0; ii < 4; ii++)
#pragma unroll
      for (int jj = 0; jj < 4; jj++)
#pragma unroll
        for (int r = 0; r < 4; r++) {
          int row = wm + ii * 16 + quad * 4 + r;
          int col = wn + jj * 16 + L;
          Sb[row * 128 + col] = f2h(acc[ii][jj][r]);
        }
  } else {
#pragma unroll
    for (int ii = 0; ii < 4; ii++)
#pragma unroll
      for (int jj = 0; jj < 4; jj++) {
        const int colp = nt * 128 + wn + jj * 16 + L;  // 0..767
        const int h    = colp >> 8;
        const int d    = colp & 255;
        const long token = (long)mt * 128 + wm + ii * 16 + quad * 4;
        const int b  = (int)(token >> 11);
        const int tk = (int)(token & 2047);
        v4u val = {f2h(acc[ii][jj][0]), f2h(acc[ii][jj][1]),
                   f2h(acc[ii][jj][2]), f2h(acc[ii][jj][3])};
        *(v4u*)(&VT[((long)(b * 3 + h) * 256 + d) * 2048 + tk]) = val;
      }
  }
}

// ---------------------------------------------------------------------------
// Softmax, one WAVE per q-row; whole row cached in registers (<=32 f32/lane).
// Single global read + single write. Block = 4 waves; grid (512, 12).
// Heavy rows (large i) dispatched first. Masked cols written as exact 0.
// ---------------------------------------------------------------------------
__global__ __launch_bounds__(256, 4)
void softmax_kernel(unsigned short* __restrict__ Sc) {
  const int tt   = threadIdx.x;
  const int wv   = tt >> 6;
  const int lane = tt & 63;
  const int bh   = (int)blockIdx.y;

  const int r = 2047 - ((int)blockIdx.x * 4 + wv);  // heavy rows first
  const int i = r >> 7;
  const int rowloc = r & 127;
  const long base = ((long)bh * 136 + (long)i * (i + 1) / 2) * 16384 + rowloc * 128;
  const int Lrow = (i + 1) * 128;
  const int nch = (i + 4) >> 2;  // ceil((i+1)/4) chunks of 512 cols

  float xs[4][8];
  float mx = -1e30f;
  for (int k = 0; k < nch; k++) {
    int c0 = k * 512 + lane * 8;
    if (c0 < Lrow) {
      int j = c0 >> 7;
      v8u v = *(const v8u*)(Sc + base + (long)j * 16384 + (c0 & 127));
#pragma unroll
      for (int e = 0; e < 8; e++) {
        float f = (c0 + e <= r) ? h2f(v[e]) * 0.0625f : -1e30f;
        xs[k][e] = f;
        mx = fmaxf(mx, f);
      }
    } else {
#pragma unroll
      for (int e = 0; e < 8; e++) xs[k][e] = -1e30f;
    }
  }
#pragma unroll
  for (int d = 1; d < 64; d <<= 1) mx = fmaxf(mx, __shfl_xor(mx, d));

  float sum = 0.f;
  for (int k = 0; k < nch; k++)
#pragma unroll
    for (int e = 0; e < 8; e++) {
      float ex = __expf(xs[k][e] - mx);  // masked: exp(-huge) = 0
      xs[k][e] = ex;
      sum += ex;
    }
#pragma unroll
  for (int d = 1; d < 64; d <<= 1) sum += __shfl_xor(sum, d);
  const float inv = 1.0f / sum;

  for (int k = 0; k < nch; k++) {
    int c0 = k * 512 + lane * 8;
    if (c0 < Lrow) {
      int j = c0 >> 7;
      v8u o;
#pragma unroll
      for (int e = 0; e < 8; e++) o[e] = f2h(xs[k][e] * inv);
      *(v8u*)(Sc + base + (long)j * 16384 + (c0 & 127)) = o;
    }
  }
}

// ---------------------------------------------------------------------------
// PV GEMM, j-parity split: partial(i,nh,par) = sum_{j==par (mod 2), j<=i}
// P(i,j).V_j, written f16 to Pp. Grid x: 64 = (16 i heavy-first)x(2 nh)x(2 par).
// ---------------------------------------------------------------------------
__global__ __launch_bounds__(256, 2)
void gemm_pv_kernel(const unsigned short* __restrict__ Sc,
                    const unsigned short* __restrict__ VT,
                    unsigned short* __restrict__ Pp) {
  __shared__ unsigned short As[4096];
  __shared__ unsigned short Bs[4096];

  const int t    = threadIdx.x;
  const int ln   = t & 63;
  const int wv   = t >> 6;
  const int quad = ln >> 4;
  const int L    = ln & 15;
  const int wm   = (wv >> 1) * 64;
  const int wn   = (wv & 1) * 64;

  const int ix  = (int)blockIdx.x;
  const int i   = 15 - (ix >> 2);  // heavy first
  const int nh  = (ix >> 1) & 1;
  const int par = ix & 1;
  const int bh  = (int)blockIdx.y;

  v4f acc[4][4];
#pragma unroll
  for (int ii = 0; ii < 4; ii++)
#pragma unroll
    for (int jj = 0; jj < 4; jj++) acc[ii][jj] = (v4f){0.f, 0.f, 0.f, 0.f};

  const int ar = t >> 2;
  const int ac = (t & 3) * 8;
  const unsigned short* Abase =
      Sc + ((long)bh * 136 + (long)i * (i + 1) / 2) * 16384 + ar * 128 + ac;
  const unsigned short* Bg =
      VT + ((long)bh * 256 + nh * 128 + ar) * 2048 + ac;
  unsigned short* la = &As[t * 8];
  unsigned short* lb = &Bs[t * 8];

  for (int j = par; j <= i; j += 2) {
    const unsigned short* Aj = Abase + (long)j * 16384;
    const unsigned short* Bj = Bg + j * 128;
#pragma unroll
    for (int k0 = 0; k0 < 128; k0 += 32) {
      gl_lds16(Aj + k0, la);
      gl_lds16(Aj + 64 * 128 + k0, la + 2048);
      gl_lds16(Bj + k0, lb);
      gl_lds16(Bj + 64 * 2048 + k0, lb + 2048);
      __syncthreads();

      v8h af[4], bfr[4];
#pragma unroll
      for (int ii = 0; ii < 4; ii++)
        af[ii] = *(const v8h*)(&As[(wm + ii * 16 + L) * 32 + quad * 8]);
#pragma unroll
      for (int jj = 0; jj < 4; jj++)
        bfr[jj] = *(const v8h*)(&Bs[(wn + jj * 16 + L) * 32 + quad * 8]);
#pragma unroll
      for (int ii = 0; ii < 4; ii++)
#pragma unroll
        for (int jj = 0; jj < 4; jj++)
          acc[ii][jj] = __builtin_amdgcn_mfma_f32_16x16x32_f16(af[ii], bfr[jj], acc[ii][jj], 0, 0, 0);
      __syncthreads();
    }
  }

  unsigned short* Pb = Pp + ((((long)bh * 16 + i) * 2 + nh) * 2 + par) * 16384;
#pragma unroll
  for (int ii = 0; ii < 4; ii++)
#pragma unroll
    for (int jj = 0; jj < 4; jj++)
#pragma unroll
      for (int r = 0; r < 4; r++) {
        int row = wm + ii * 16 + quad * 4 + r;
        int col = wn + jj * 16 + L;
        Pb[row * 128 + col] = f2h(acc[ii][jj][r]);
      }
}

// ---------------------------------------------------------------------------
// Combine the two parity partials -> AO. Grid (32 = 16i x 2nh, 12).
// Thread: row = tid>>1, 64-col half (tid&1). 8 x v8u.
// ---------------------------------------------------------------------------
__global__ __launch_bounds__(256, 4)
void pv_combine_kernel(const unsigned short* __restrict__ Pp,
                       unsigned short* __restrict__ AO) {
  const int i  = (int)blockIdx.x >> 1;
  const int nh = (int)blockIdx.x & 1;
  const int bh = (int)blockIdx.y;
  const int b  = bh / 3, h = bh % 3;

  const int tid = threadIdx.x;
  const int row = tid >> 1;
  const int cs  = (tid & 1) * 64;

  const unsigned short* P0 = Pp + ((((long)bh * 16 + i) * 2 + nh) * 2 + 0) * 16384 + row * 128 + cs;
  const unsigned short* P1 = P0 + 16384;
  unsigned short* Or = AO + ((long)b * 2048 + i * 128 + row) * 768 + h * 256 + nh * 128 + cs;
#pragma unroll
  for (int q = 0; q < 8; q++) {
    v8u a = *(const v8u*)(P0 + q * 8);
    v8u c = *(const v8u*)(P1 + q * 8);
    v8u o;
#pragma unroll
    for (int e = 0; e < 8; e++) o[e] = f2h(h2f(a[e]) + h2f(c[e]));
    *(v8u*)(Or + q * 8) = o;
  }
}

// ---------------------------------------------------------------------------
extern "C" void kernel_launch(void* const* d_in, const int* in_sizes, int n_in,
                              void* d_out, int out_size, void* d_ws, size_t ws_size,
                              hipStream_t stream) {
  const float* X     = (const float*)d_in[0];  // [4,2048,768] f32
  const float* Wqkv  = (const float*)d_in[1];  // [2304,768]   f32
  const float* Wproj = (const float*)d_in[2];  // [768,768]    f32
  float* out = (float*)d_out;                  // [4,2048,768] f32

  const size_t SZ_QK = (size_t)8192 * 1536 * 2;       // 25.2 MB
  const size_t SZ_VT = (size_t)3072 * 2048 * 2;       // 12.6 MB
  const size_t SZ_SC = (size_t)12 * 136 * 16384 * 2;  // 53.5 MB
  const size_t SZ_AO = (size_t)8192 * 768 * 2;        // 12.6 MB
  const size_t SZ_WQ = (size_t)2304 * 768 * 2;        //  3.5 MB

  char* ws = (char*)d_ws;
  unsigned short* QKb = (unsigned short*)ws;
  unsigned short* Ppb = QKb;  // alias: QK dead after scv; Pp = 12*16*2*2*16384*2 B == SZ_QK
  unsigned short* VTb = (unsigned short*)(ws + SZ_QK);
  unsigned short* Scb = (unsigned short*)(ws + SZ_QK + SZ_VT);
  unsigned short* AOb = (unsigned short*)(ws + SZ_QK + SZ_VT + SZ_SC);
  unsigned short* Xb  = AOb;  // alias: Xb dead after scv; AO written by combine (later)
  unsigned short* Wqb = (unsigned short*)(ws + SZ_QK + SZ_VT + SZ_SC + SZ_AO);
  unsigned short* Wpb = (unsigned short*)(ws + SZ_QK + SZ_VT + SZ_SC + SZ_AO + SZ_WQ);

  dim3 blk(256, 1, 1);
  // 0) one-time f32 -> f16 conversions (single launch)
  cvt3_kernel<<<dim3(4224, 1, 1), blk, 0, stream>>>(X, Wqkv, Wproj, Xb, Wqb, Wpb);
  // 1) Q,K projection (V folded into scv), 256^2 8-phase schedule, one round
  qkv8_kernel<<<dim3(6, 32, 1), dim3(512, 1, 1), 0, stream>>>(Xb, Wqb, QKb);
  // 2) score tiles + V projection in ONE dispatch
  scv_kernel<<<dim3(168, 12, 1), blk, 0, stream>>>(QKb, Xb, Wqb, Scb, VTb);
  softmax_kernel<<<dim3(512, 12, 1), blk, 0, stream>>>(Scb);
  gemm_pv_kernel<<<dim3(64, 12, 1), blk, 0, stream>>>(Scb, VTb, Ppb);
  pv_combine_kernel<<<dim3(32, 12, 1), blk, 0, stream>>>(Ppb, AOb);
  // 3) output projection, f32 store
  gemm_proj_kernel<<<dim3(6, 64, 1), blk, 0, stream>>>(AOb, Wpb, out);
}

// Round 4
// 243.615 us; speedup vs baseline: 1.0902x; 1.0555x over previous
//
#include <hip/hip_runtime.h>

using v8h = __attribute__((ext_vector_type(8))) _Float16;       // 8 f16 MFMA frag
using v4f = __attribute__((ext_vector_type(4))) float;          // MFMA acc
using v4u = __attribute__((ext_vector_type(4))) unsigned short; // 8B packed
using v8u = __attribute__((ext_vector_type(8))) unsigned short; // 16B copy

// fp32 <-> fp16
__device__ __forceinline__ unsigned short f2h(float x) {
  _Float16 h = (_Float16)x;
  return __builtin_bit_cast(unsigned short, h);
}
__device__ __forceinline__ float h2f(unsigned short u) {
  return (float)__builtin_bit_cast(_Float16, u);
}

// async global -> LDS, 16 bytes per lane (global_load_lds_dwordx4)
__device__ __forceinline__ void gl_lds16(const unsigned short* g, unsigned short* l) {
  __builtin_amdgcn_global_load_lds(
      (const __attribute__((address_space(1))) unsigned int*)g,
      (__attribute__((address_space(3))) unsigned int*)l, 16, 0, 0);
}

// ---------------------------------------------------------------------------
// All three f32 -> f16 conversions in ONE launch. Grid 4224 x 256, exact
// multiples (3072 / 864 / 288 blocks), 8 elems/thread, no guards needed.
// ---------------------------------------------------------------------------
__global__ void cvt3_kernel(const float* __restrict__ X,
                            const float* __restrict__ Wq,
                            const float* __restrict__ Wp,
                            unsigned short* __restrict__ Xb,
                            unsigned short* __restrict__ Wqb,
                            unsigned short* __restrict__ Wpb) {
  const int blk = (int)blockIdx.x;
  const float* src;
  unsigned short* dst;
  int i;
  if (blk < 3072)      { src = X;  dst = Xb;  i = blk * 256 + threadIdx.x; }
  else if (blk < 3936) { src = Wq; dst = Wqb; i = (blk - 3072) * 256 + threadIdx.x; }
  else                 { src = Wp; dst = Wpb; i = (blk - 3936) * 256 + threadIdx.x; }
  const float* p = src + (size_t)i * 8;
  float4 a = *(const float4*)p;
  float4 b = *(const float4*)(p + 4);
  v8u o = {f2h(a.x), f2h(a.y), f2h(a.z), f2h(a.w),
           f2h(b.x), f2h(b.y), f2h(b.z), f2h(b.w)};
  *(v8u*)(dst + (size_t)i * 8) = o;
}

// ---------------------------------------------------------------------------
// QK projection: 256x256 tile, BK=64, 512 thr = 8 waves (2M x 4N),
// 8-phase counted-vmcnt schedule + XOR swizzle + setprio.
// A[8192][768] f16, Bw rows 0..1535 (Q,K out-features).
// Grid (6, 32) = 192 blocks -> ONE round at 1 block/CU (128KB LDS).
// ---------------------------------------------------------------------------
__global__ __launch_bounds__(512, 2)
void qkv8_kernel(const unsigned short* __restrict__ A,
                 const unsigned short* __restrict__ Bw,
                 unsigned short* __restrict__ QK) {
  __shared__ unsigned short sm[65536];  // 128 KB
  const int t    = (int)threadIdx.x;
  const int ln   = t & 63;
  const int wv   = t >> 6;
  const int quad = ln >> 4;
  const int L    = ln & 15;
  const int wm   = wv >> 2;   // 0..1 -> 128-row half of the 256-row tile
  const int wn   = wv & 3;    // 0..3 -> 64-col stripe
  const long m0  = (long)blockIdx.y * 256;
  const long n0  = (long)blockIdx.x * 256;

  // Staging: thread t stages 16B at LDS linear slot t; pre-swizzled GLOBAL
  // source so phys slot p of row r holds logical k-slot p ^ (r&7).
  const int srow = t >> 3;                        // 0..63
  const int scol = ((t & 7) ^ (srow & 7)) * 8;    // shorts
  const unsigned short* Ath = A + (m0 + srow) * 768 + scol;
  const unsigned short* Bth = Bw + (n0 + srow) * 768 + scol;
  unsigned short* lth = &sm[t * 8];

  // Read: logical slot (ks*4+quad) lives at phys slot ^(row&7); row&7 == L&7.
  const int l7   = L & 7;
  const int sl0  = ((0 + quad) ^ l7) * 8;   // ks=0, shorts
  const int sl1  = ((4 + quad) ^ l7) * 8;   // ks=1
  const int arow = (wm * 128 + L) * 64;     // shorts; +mq*4096, +i*1024
  const int brow = (wn * 64 + L) * 64;      // shorts; +nh*2048, +j*1024

  v4f acc[8][4];
#pragma unroll
  for (int i = 0; i < 8; i++)
#pragma unroll
    for (int j = 0; j < 4; j++) acc[i][j] = (v4f){0.f, 0.f, 0.f, 0.f};

  auto stA = [&](int tile, int h) {
    if (tile >= 12) return;
    const unsigned short* g = Ath + (h * 128) * 768 + tile * 64;
    unsigned short* l = lth + (tile & 1) * 32768 + h * 8192;
    gl_lds16(g, l);
    gl_lds16(g + 64 * 768, l + 4096);
  };
  auto stB = [&](int tile, int h) {
    if (tile >= 12) return;
    const unsigned short* g = Bth + (h * 128) * 768 + tile * 64;
    unsigned short* l = lth + (tile & 1) * 32768 + 16384 + h * 8192;
    gl_lds16(g, l);
    gl_lds16(g + 64 * 768, l + 4096);
  };

  // prologue: tile0 complete + 3 half-tiles of tile1 in flight (6 ticks)
  stB(0, 0); stB(0, 1); stA(0, 0); stA(0, 1);
  stB(1, 0); stB(1, 1); stA(1, 0);
  asm volatile("s_waitcnt vmcnt(6)" ::: "memory");
  __builtin_amdgcn_s_barrier();
  __builtin_amdgcn_sched_barrier(0);

#pragma unroll 2
  for (int kt = 0; kt < 12; ++kt) {
    const unsigned short* sA = &sm[(kt & 1) * 32768];
    const unsigned short* sB = sA + 16384;
    v8h af[4][2], b0[2][2], b1[2][2];

    // ---- phase 1: quadrant (mq0, nh0) — 12 ds_read_b128 + 1 half stage
#pragma unroll
    for (int i = 0; i < 4; i++) {
      af[i][0] = *(const v8h*)&sA[arow + i * 1024 + sl0];
      af[i][1] = *(const v8h*)&sA[arow + i * 1024 + sl1];
    }
#pragma unroll
    for (int j = 0; j < 2; j++) {
      b0[j][0] = *(const v8h*)&sB[brow + j * 1024 + sl0];
      b0[j][1] = *(const v8h*)&sB[brow + j * 1024 + sl1];
    }
    stA(kt + 1, 1);
    __builtin_amdgcn_s_barrier();
    asm volatile("s_waitcnt lgkmcnt(0)" ::: "memory");
    __builtin_amdgcn_sched_barrier(0);
    __builtin_amdgcn_s_setprio(1);
#pragma unroll
    for (int i = 0; i < 4; i++)
#pragma unroll
      for (int j = 0; j < 2; j++) {
        acc[i][j] = __builtin_amdgcn_mfma_f32_16x16x32_f16(af[i][0], b0[j][0], acc[i][j], 0, 0, 0);
        acc[i][j] = __builtin_amdgcn_mfma_f32_16x16x32_f16(af[i][1], b0[j][1], acc[i][j], 0, 0, 0);
      }
    __builtin_amdgcn_s_setprio(0);
    __builtin_amdgcn_s_barrier();
    __builtin_amdgcn_sched_barrier(0);

    // ---- phase 2: (mq0, nh1) — 4 ds_read_b128
#pragma unroll
    for (int j = 0; j < 2; j++) {
      b1[j][0] = *(const v8h*)&sB[brow + 2048 + j * 1024 + sl0];
      b1[j][1] = *(const v8h*)&sB[brow + 2048 + j * 1024 + sl1];
    }
    __builtin_amdgcn_s_barrier();
    asm volatile("s_waitcnt lgkmcnt(0)" ::: "memory");
    __builtin_amdgcn_sched_barrier(0);
    __builtin_amdgcn_s_setprio(1);
#pragma unroll
    for (int i = 0; i < 4; i++)
#pragma unroll
      for (int j = 0; j < 2; j++) {
        acc[i][2 + j] = __builtin_amdgcn_mfma_f32_16x16x32_f16(af[i][0], b1[j][0], acc[i][2 + j], 0, 0, 0);
        acc[i][2 + j] = __builtin_amdgcn_mfma_f32_16x16x32_f16(af[i][1], b1[j][1], acc[i][2 + j], 0, 0, 0);
      }
    __builtin_amdgcn_s_setprio(0);
    __builtin_amdgcn_s_barrier();
    __builtin_amdgcn_sched_barrier(0);

    // ---- phase 3: (mq1, nh1) — 8 ds_read_b128 + 1 half stage
#pragma unroll
    for (int i = 0; i < 4; i++) {
      af[i][0] = *(const v8h*)&sA[arow + 4096 + i * 1024 + sl0];
      af[i][1] = *(const v8h*)&sA[arow + 4096 + i * 1024 + sl1];
    }
    stB(kt + 2, 0);
    __builtin_amdgcn_s_barrier();
    asm volatile("s_waitcnt lgkmcnt(0)" ::: "memory");
    __builtin_amdgcn_sched_barrier(0);
    __builtin_amdgcn_s_setprio(1);
#pragma unroll
    for (int i = 0; i < 4; i++)
#pragma unroll
      for (int j = 0; j < 2; j++) {
        acc[4 + i][2 + j] = __builtin_amdgcn_mfma_f32_16x16x32_f16(af[i][0], b1[j][0], acc[4 + i][2 + j], 0, 0, 0);
        acc[4 + i][2 + j] = __builtin_amdgcn_mfma_f32_16x16x32_f16(af[i][1], b1[j][1], acc[4 + i][2 + j], 0, 0, 0);
      }
    __builtin_amdgcn_s_setprio(0);
    __builtin_amdgcn_s_barrier();
    __builtin_amdgcn_sched_barrier(0);

    // ---- phase 4: (mq1, nh0) — reuses af (ph3) and b0 (ph1); 2 half stages
    stB(kt + 2, 1);
    stA(kt + 2, 0);
    __builtin_amdgcn_s_barrier();
    __builtin_amdgcn_sched_barrier(0);
    __builtin_amdgcn_s_setprio(1);
#pragma unroll
    for (int i = 0; i < 4; i++)
#pragma unroll
      for (int j = 0; j < 2; j++) {
        acc[4 + i][j] = __builtin_amdgcn_mfma_f32_16x16x32_f16(af[i][0], b0[j][0], acc[4 + i][j], 0, 0, 0);
        acc[4 + i][j] = __builtin_amdgcn_mfma_f32_16x16x32_f16(af[i][1], b0[j][1], acc[4 + i][j], 0, 0, 0);
      }
    __builtin_amdgcn_s_setprio(0);
    if (kt + 2 < 12)      { asm volatile("s_waitcnt vmcnt(6)" ::: "memory"); }
    else if (kt + 1 < 12) { asm volatile("s_waitcnt vmcnt(0)" ::: "memory"); }
    __builtin_amdgcn_s_barrier();
    __builtin_amdgcn_sched_barrier(0);
  }

  // epilogue: C/D frag mapping col = L, row = quad*4 + r; all cols < 1536
#pragma unroll
  for (int mi = 0; mi < 8; mi++) {
    const long row = m0 + wm * 128 + (mi >> 2) * 64 + (mi & 3) * 16 + quad * 4;
#pragma unroll
    for (int nj = 0; nj < 4; nj++) {
      const long col = n0 + wn * 64 + nj * 16 + L;
#pragma unroll
      for (int r = 0; r < 4; r++)
        QK[(row + r) * 1536 + col] = f2h(acc[mi][nj][r]);
    }
  }
}

// ---------------------------------------------------------------------------
// COMBINED score + V-projection, 256^2 tiles, 8-phase schedule (same verified
// template as qkv8, parameterized base/stride/K-depth). Grid (528, 1):
//   x < 96  : V-projection. mt = x&31 (M-tile of 8192/256), nt = x>>5 (of 3).
//             A = Xb rows mt*256, stride 768; B = Wq rows 1536+nt*256. NT=12.
//             Epilogue -> VT transposed (v4u packed).
//   x >= 96 : score tile. s = x-96: bh = s/36, packed (I,J) from s%36.
//             A = QK rows b*2048+I*256 col h*256; B = +768 (K). NT=4.
//             Epilogue -> four 128^2 sub-tiles into packed lower-tri Sc
//             (slot = i128(i128+1)/2 + j128), skipping the above-diagonal
//             sub-tile on diagonal 256-tiles. Downstream layout UNCHANGED.
// V blocks (12 K-units) first, scores (4 units) fill -> makespan ~12 units.
// ---------------------------------------------------------------------------
__global__ __launch_bounds__(512, 2)
void scv8_kernel(const unsigned short* __restrict__ QK,
                 const unsigned short* __restrict__ Xb,
                 const unsigned short* __restrict__ Wq,
                 unsigned short* __restrict__ Sc,
                 unsigned short* __restrict__ VT) {
  __shared__ unsigned short sm[65536];  // 128 KB
  const int t    = (int)threadIdx.x;
  const int ln   = t & 63;
  const int wv   = t >> 6;
  const int quad = ln >> 4;
  const int L    = ln & 15;
  const int wm   = wv >> 2;   // 0..1 -> 128-row half
  const int wn   = wv & 3;    // 0..3 -> 64-col stripe

  const int x = (int)blockIdx.x;
  const bool isV = (x < 96);
  int NT, Ihi = 0, Jhi = 0, bh = 0, mt = 0, nt = 0;
  const unsigned short* Abase;
  const unsigned short* Bbase;
  long astr, bstr;

  if (isV) {
    mt = x & 31;            // 0..31
    nt = x >> 5;            // 0..2
    Abase = Xb + (long)mt * 256 * 768;
    Bbase = Wq + (long)(1536 + nt * 256) * 768;
    astr = 768; bstr = 768; NT = 12;
  } else {
    int s = x - 96;         // 0..431
    bh = s / 36;
    int slot = s % 36;
    while (slot >= Ihi + 1) { slot -= Ihi + 1; Ihi++; }
    Jhi = slot;             // Ihi,Jhi in 0..7, Jhi <= Ihi
    const int b = bh / 3, h = bh % 3;
    Abase = QK + ((long)b * 2048 + Ihi * 256) * 1536 + h * 256;
    Bbase = QK + ((long)b * 2048 + Jhi * 256) * 1536 + 768 + h * 256;
    astr = 1536; bstr = 1536; NT = 4;
  }

  const int srow = t >> 3;                        // 0..63
  const int scol = ((t & 7) ^ (srow & 7)) * 8;    // shorts
  const unsigned short* Ath = Abase + (long)srow * astr + scol;
  const unsigned short* Bth = Bbase + (long)srow * bstr + scol;
  unsigned short* lth = &sm[t * 8];

  const int l7   = L & 7;
  const int sl0  = ((0 + quad) ^ l7) * 8;
  const int sl1  = ((4 + quad) ^ l7) * 8;
  const int arow = (wm * 128 + L) * 64;
  const int brow = (wn * 64 + L) * 64;

  v4f acc[8][4];
#pragma unroll
  for (int i = 0; i < 8; i++)
#pragma unroll
    for (int j = 0; j < 4; j++) acc[i][j] = (v4f){0.f, 0.f, 0.f, 0.f};

  auto stA = [&](int tile, int h) {
    if (tile >= NT) return;
    const unsigned short* g = Ath + (long)(h * 128) * astr + tile * 64;
    unsigned short* l = lth + (tile & 1) * 32768 + h * 8192;
    gl_lds16(g, l);
    gl_lds16(g + 64 * astr, l + 4096);
  };
  auto stB = [&](int tile, int h) {
    if (tile >= NT) return;
    const unsigned short* g = Bth + (long)(h * 128) * bstr + tile * 64;
    unsigned short* l = lth + (tile & 1) * 32768 + 16384 + h * 8192;
    gl_lds16(g, l);
    gl_lds16(g + 64 * bstr, l + 4096);
  };

  // prologue: tile0 complete + 3 half-tiles of tile1 in flight (NT >= 2)
  stB(0, 0); stB(0, 1); stA(0, 0); stA(0, 1);
  stB(1, 0); stB(1, 1); stA(1, 0);
  asm volatile("s_waitcnt vmcnt(6)" ::: "memory");
  __builtin_amdgcn_s_barrier();
  __builtin_amdgcn_sched_barrier(0);

#pragma unroll 2
  for (int kt = 0; kt < NT; ++kt) {
    const unsigned short* sA = &sm[(kt & 1) * 32768];
    const unsigned short* sB = sA + 16384;
    v8h af[4][2], b0[2][2], b1[2][2];

    // ---- phase 1: (mq0, nh0)
#pragma unroll
    for (int i = 0; i < 4; i++) {
      af[i][0] = *(const v8h*)&sA[arow + i * 1024 + sl0];
      af[i][1] = *(const v8h*)&sA[arow + i * 1024 + sl1];
    }
#pragma unroll
    for (int j = 0; j < 2; j++) {
      b0[j][0] = *(const v8h*)&sB[brow + j * 1024 + sl0];
      b0[j][1] = *(const v8h*)&sB[brow + j * 1024 + sl1];
    }
    stA(kt + 1, 1);
    __builtin_amdgcn_s_barrier();
    asm volatile("s_waitcnt lgkmcnt(0)" ::: "memory");
    __builtin_amdgcn_sched_barrier(0);
    __builtin_amdgcn_s_setprio(1);
#pragma unroll
    for (int i = 0; i < 4; i++)
#pragma unroll
      for (int j = 0; j < 2; j++) {
        acc[i][j] = __builtin_amdgcn_mfma_f32_16x16x32_f16(af[i][0], b0[j][0], acc[i][j], 0, 0, 0);
        acc[i][j] = __builtin_amdgcn_mfma_f32_16x16x32_f16(af[i][1], b0[j][1], acc[i][j], 0, 0, 0);
      }
    __builtin_amdgcn_s_setprio(0);
    __builtin_amdgcn_s_barrier();
    __builtin_amdgcn_sched_barrier(0);

    // ---- phase 2: (mq0, nh1)
#pragma unroll
    for (int j = 0; j < 2; j++) {
      b1[j][0] = *(const v8h*)&sB[brow + 2048 + j * 1024 + sl0];
      b1[j][1] = *(const v8h*)&sB[brow + 2048 + j * 1024 + sl1];
    }
    __builtin_amdgcn_s_barrier();
    asm volatile("s_waitcnt lgkmcnt(0)" ::: "memory");
    __builtin_amdgcn_sched_barrier(0);
    __builtin_amdgcn_s_setprio(1);
#pragma unroll
    for (int i = 0; i < 4; i++)
#pragma unroll
      for (int j = 0; j < 2; j++) {
        acc[i][2 + j] = __builtin_amdgcn_mfma_f32_16x16x32_f16(af[i][0], b1[j][0], acc[i][2 + j], 0, 0, 0);
        acc[i][2 + j] = __builtin_amdgcn_mfma_f32_16x16x32_f16(af[i][1], b1[j][1], acc[i][2 + j], 0, 0, 0);
      }
    __builtin_amdgcn_s_setprio(0);
    __builtin_amdgcn_s_barrier();
    __builtin_amdgcn_sched_barrier(0);

    // ---- phase 3: (mq1, nh1)
#pragma unroll
    for (int i = 0; i < 4; i++) {
      af[i][0] = *(const v8h*)&sA[arow + 4096 + i * 1024 + sl0];
      af[i][1] = *(const v8h*)&sA[arow + 4096 + i * 1024 + sl1];
    }
    stB(kt + 2, 0);
    __builtin_amdgcn_s_barrier();
    asm volatile("s_waitcnt lgkmcnt(0)" ::: "memory");
    __builtin_amdgcn_sched_barrier(0);
    __builtin_amdgcn_s_setprio(1);
#pragma unroll
    for (int i = 0; i < 4; i++)
#pragma unroll
      for (int j = 0; j < 2; j++) {
        acc[4 + i][2 + j] = __builtin_amdgcn_mfma_f32_16x16x32_f16(af[i][0], b1[j][0], acc[4 + i][2 + j], 0, 0, 0);
        acc[4 + i][2 + j] = __builtin_amdgcn_mfma_f32_16x16x32_f16(af[i][1], b1[j][1], acc[4 + i][2 + j], 0, 0, 0);
      }
    __builtin_amdgcn_s_setprio(0);
    __builtin_amdgcn_s_barrier();
    __builtin_amdgcn_sched_barrier(0);

    // ---- phase 4: (mq1, nh0) — reuses af (ph3) and b0 (ph1)
    stB(kt + 2, 1);
    stA(kt + 2, 0);
    __builtin_amdgcn_s_barrier();
    __builtin_amdgcn_sched_barrier(0);
    __builtin_amdgcn_s_setprio(1);
#pragma unroll
    for (int i = 0; i < 4; i++)
#pragma unroll
      for (int j = 0; j < 2; j++) {
        acc[4 + i][j] = __builtin_amdgcn_mfma_f32_16x16x32_f16(af[i][0], b0[j][0], acc[4 + i][j], 0, 0, 0);
        acc[4 + i][j] = __builtin_amdgcn_mfma_f32_16x16x32_f16(af[i][1], b0[j][1], acc[4 + i][j], 0, 0, 0);
      }
    __builtin_amdgcn_s_setprio(0);
    if (kt + 2 < NT)      { asm volatile("s_waitcnt vmcnt(6)" ::: "memory"); }
    else if (kt + 1 < NT) { asm volatile("s_waitcnt vmcnt(0)" ::: "memory"); }
    __builtin_amdgcn_s_barrier();
    __builtin_amdgcn_sched_barrier(0);
  }

  if (isV) {
#pragma unroll
    for (int mi = 0; mi < 8; mi++) {
      const long token = (long)mt * 256 + wm * 128 + (mi >> 2) * 64 + (mi & 3) * 16 + quad * 4;
      const int b  = (int)(token >> 11);
      const int tk = (int)(token & 2047);
#pragma unroll
      for (int nj = 0; nj < 4; nj++) {
        const int colp = nt * 256 + wn * 64 + nj * 16 + L;  // 0..767
        const int h    = colp >> 8;
        const int d    = colp & 255;
        v4u val = {f2h(acc[mi][nj][0]), f2h(acc[mi][nj][1]),
                   f2h(acc[mi][nj][2]), f2h(acc[mi][nj][3])};
        *(v4u*)(&VT[((long)(b * 3 + h) * 256 + d) * 2048 + tk]) = val;
      }
    }
  } else {
    const int di = wm;        // row sub-tile 0/1
    const int dj = wn >> 1;   // col sub-tile 0/1
    const int i128 = 2 * Ihi + di;
    const int j128 = 2 * Jhi + dj;
    if (j128 <= i128) {       // skip above-diagonal sub-tile on diagonal tiles
      unsigned short* Sb = Sc + ((long)bh * 136 + (long)i128 * (i128 + 1) / 2 + j128) * 16384;
#pragma unroll
      for (int mi = 0; mi < 8; mi++) {
        const int subrow = (mi >> 2) * 64 + (mi & 3) * 16 + quad * 4;
#pragma unroll
        for (int nj = 0; nj < 4; nj++) {
          const int subcol = (wn & 1) * 64 + nj * 16 + L;
#pragma unroll
          for (int r = 0; r < 4; r++)
            Sb[(subrow + r) * 128 + subcol] = f2h(acc[mi][nj][r]);
        }
      }
    }
  }
}

// ---------------------------------------------------------------------------
// f16 GEMM, m97 recipe (output projection): C[m,n] = sum_k A[m,k]*Bw[n,k],
// 128x128 tile, BK=32, f32 store.
// ---------------------------------------------------------------------------
__global__ __launch_bounds__(256, 2)
void gemm_proj_kernel(const unsigned short* __restrict__ A,
                      const unsigned short* __restrict__ Bw,
                      float* __restrict__ C) {
  __shared__ unsigned short As[4096];
  __shared__ unsigned short Bs[4096];

  const int t    = threadIdx.x;
  const int ln   = t & 63;
  const int wv   = t >> 6;
  const int quad = ln >> 4;
  const int L    = ln & 15;
  const int wm   = (wv >> 1) * 64;
  const int wn   = (wv & 1) * 64;
  const long m0  = (long)blockIdx.y * 128;
  const long n0  = (long)blockIdx.x * 128;

  v4f acc[4][4];
#pragma unroll
  for (int i = 0; i < 4; i++)
#pragma unroll
    for (int j = 0; j < 4; j++) acc[i][j] = (v4f){0.f, 0.f, 0.f, 0.f};

  const int ar = t >> 2;
  const int ac = (t & 3) * 8;
  const unsigned short* Ag = A + (m0 + ar) * 768 + ac;
  const unsigned short* Bg = Bw + (n0 + ar) * 768 + ac;
  unsigned short* la = &As[t * 8];
  unsigned short* lb = &Bs[t * 8];
  const long rowskip = 64L * 768;

  for (int k0 = 0; k0 < 768; k0 += 32) {
    gl_lds16(Ag + k0, la);
    gl_lds16(Ag + rowskip + k0, la + 2048);
    gl_lds16(Bg + k0, lb);
    gl_lds16(Bg + rowskip + k0, lb + 2048);
    __syncthreads();

    v8h af[4], bfr[4];
#pragma unroll
    for (int i = 0; i < 4; i++)
      af[i] = *(const v8h*)(&As[(wm + i * 16 + L) * 32 + quad * 8]);
#pragma unroll
    for (int j = 0; j < 4; j++)
      bfr[j] = *(const v8h*)(&Bs[(wn + j * 16 + L) * 32 + quad * 8]);
#pragma unroll
    for (int i = 0; i < 4; i++)
#pragma unroll
      for (int j = 0; j < 4; j++)
        acc[i][j] = __builtin_amdgcn_mfma_f32_16x16x32_f16(af[i], bfr[j], acc[i][j], 0, 0, 0);
    __syncthreads();
  }

#pragma unroll
  for (int i = 0; i < 4; i++)
#pragma unroll
    for (int j = 0; j < 4; j++)
#pragma unroll
      for (int r = 0; r < 4; r++) {
        long row = m0 + wm + i * 16 + quad * 4 + r;
        long col = n0 + wn + j * 16 + L;
        C[row * 768 + col] = acc[i][j][r];
      }
}

// ---------------------------------------------------------------------------
// Softmax, one WAVE per q-row; whole row cached in registers (<=32 f32/lane).
// Single global read + single write. Block = 4 waves; grid (512, 12).
// Heavy rows (large i) dispatched first. Masked cols written as exact 0.
// ---------------------------------------------------------------------------
__global__ __launch_bounds__(256, 4)
void softmax_kernel(unsigned short* __restrict__ Sc) {
  const int tt   = threadIdx.x;
  const int wv   = tt >> 6;
  const int lane = tt & 63;
  const int bh   = (int)blockIdx.y;

  const int r = 2047 - ((int)blockIdx.x * 4 + wv);  // heavy rows first
  const int i = r >> 7;
  const int rowloc = r & 127;
  const long base = ((long)bh * 136 + (long)i * (i + 1) / 2) * 16384 + rowloc * 128;
  const int Lrow = (i + 1) * 128;
  const int nch = (i + 4) >> 2;  // ceil((i+1)/4) chunks of 512 cols

  float xs[4][8];
  float mx = -1e30f;
  for (int k = 0; k < nch; k++) {
    int c0 = k * 512 + lane * 8;
    if (c0 < Lrow) {
      int j = c0 >> 7;
      v8u v = *(const v8u*)(Sc + base + (long)j * 16384 + (c0 & 127));
#pragma unroll
      for (int e = 0; e < 8; e++) {
        float f = (c0 + e <= r) ? h2f(v[e]) * 0.0625f : -1e30f;
        xs[k][e] = f;
        mx = fmaxf(mx, f);
      }
    } else {
#pragma unroll
      for (int e = 0; e < 8; e++) xs[k][e] = -1e30f;
    }
  }
#pragma unroll
  for (int d = 1; d < 64; d <<= 1) mx = fmaxf(mx, __shfl_xor(mx, d));

  float sum = 0.f;
  for (int k = 0; k < nch; k++)
#pragma unroll
    for (int e = 0; e < 8; e++) {
      float ex = __expf(xs[k][e] - mx);  // masked: exp(-huge) = 0
      xs[k][e] = ex;
      sum += ex;
    }
#pragma unroll
  for (int d = 1; d < 64; d <<= 1) sum += __shfl_xor(sum, d);
  const float inv = 1.0f / sum;

  for (int k = 0; k < nch; k++) {
    int c0 = k * 512 + lane * 8;
    if (c0 < Lrow) {
      int j = c0 >> 7;
      v8u o;
#pragma unroll
      for (int e = 0; e < 8; e++) o[e] = f2h(xs[k][e] * inv);
      *(v8u*)(Sc + base + (long)j * 16384 + (c0 & 127)) = o;
    }
  }
}

// ---------------------------------------------------------------------------
// PV GEMM, j-parity split: partial(i,nh,par) = sum_{j==par (mod 2), j<=i}
// P(i,j).V_j, written f16 to Pp. Grid x: 64 = (16 i heavy-first)x(2 nh)x(2 par).
// ---------------------------------------------------------------------------
__global__ __launch_bounds__(256, 2)
void gemm_pv_kernel(const unsigned short* __restrict__ Sc,
                    const unsigned short* __restrict__ VT,
                    unsigned short* __restrict__ Pp) {
  __shared__ unsigned short As[4096];
  __shared__ unsigned short Bs[4096];

  const int t    = threadIdx.x;
  const int ln   = t & 63;
  const int wv   = t >> 6;
  const int quad = ln >> 4;
  const int L    = ln & 15;
  const int wm   = (wv >> 1) * 64;
  const int wn   = (wv & 1) * 64;

  const int ix  = (int)blockIdx.x;
  const int i   = 15 - (ix >> 2);  // heavy first
  const int nh  = (ix >> 1) & 1;
  const int par = ix & 1;
  const int bh  = (int)blockIdx.y;

  v4f acc[4][4];
#pragma unroll
  for (int ii = 0; ii < 4; ii++)
#pragma unroll
    for (int jj = 0; jj < 4; jj++) acc[ii][jj] = (v4f){0.f, 0.f, 0.f, 0.f};

  const int ar = t >> 2;
  const int ac = (t & 3) * 8;
  const unsigned short* Abase =
      Sc + ((long)bh * 136 + (long)i * (i + 1) / 2) * 16384 + ar * 128 + ac;
  const unsigned short* Bg =
      VT + ((long)bh * 256 + nh * 128 + ar) * 2048 + ac;
  unsigned short* la = &As[t * 8];
  unsigned short* lb = &Bs[t * 8];

  for (int j = par; j <= i; j += 2) {
    const unsigned short* Aj = Abase + (long)j * 16384;
    const unsigned short* Bj = Bg + j * 128;
#pragma unroll
    for (int k0 = 0; k0 < 128; k0 += 32) {
      gl_lds16(Aj + k0, la);
      gl_lds16(Aj + 64 * 128 + k0, la + 2048);
      gl_lds16(Bj + k0, lb);
      gl_lds16(Bj + 64 * 2048 + k0, lb + 2048);
      __syncthreads();

      v8h af[4], bfr[4];
#pragma unroll
      for (int ii = 0; ii < 4; ii++)
        af[ii] = *(const v8h*)(&As[(wm + ii * 16 + L) * 32 + quad * 8]);
#pragma unroll
      for (int jj = 0; jj < 4; jj++)
        bfr[jj] = *(const v8h*)(&Bs[(wn + jj * 16 + L) * 32 + quad * 8]);
#pragma unroll
      for (int ii = 0; ii < 4; ii++)
#pragma unroll
        for (int jj = 0; jj < 4; jj++)
          acc[ii][jj] = __builtin_amdgcn_mfma_f32_16x16x32_f16(af[ii], bfr[jj], acc[ii][jj], 0, 0, 0);
      __syncthreads();
    }
  }

  unsigned short* Pb = Pp + ((((long)bh * 16 + i) * 2 + nh) * 2 + par) * 16384;
#pragma unroll
  for (int ii = 0; ii < 4; ii++)
#pragma unroll
    for (int jj = 0; jj < 4; jj++)
#pragma unroll
      for (int r = 0; r < 4; r++) {
        int row = wm + ii * 16 + quad * 4 + r;
        int col = wn + jj * 16 + L;
        Pb[row * 128 + col] = f2h(acc[ii][jj][r]);
      }
}

// ---------------------------------------------------------------------------
// Combine the two parity partials -> AO. Grid (32 = 16i x 2nh, 12).
// Thread: row = tid>>1, 64-col half (tid&1). 8 x v8u.
// ---------------------------------------------------------------------------
__global__ __launch_bounds__(256, 4)
void pv_combine_kernel(const unsigned short* __restrict__ Pp,
                       unsigned short* __restrict__ AO) {
  const int i  = (int)blockIdx.x >> 1;
  const int nh = (int)blockIdx.x & 1;
  const int bh = (int)blockIdx.y;
  const int b  = bh / 3, h = bh % 3;

  const int tid = threadIdx.x;
  const int row = tid >> 1;
  const int cs  = (tid & 1) * 64;

  const unsigned short* P0 = Pp + ((((long)bh * 16 + i) * 2 + nh) * 2 + 0) * 16384 + row * 128 + cs;
  const unsigned short* P1 = P0 + 16384;
  unsigned short* Or = AO + ((long)b * 2048 + i * 128 + row) * 768 + h * 256 + nh * 128 + cs;
#pragma unroll
  for (int q = 0; q < 8; q++) {
    v8u a = *(const v8u*)(P0 + q * 8);
    v8u c = *(const v8u*)(P1 + q * 8);
    v8u o;
#pragma unroll
    for (int e = 0; e < 8; e++) o[e] = f2h(h2f(a[e]) + h2f(c[e]));
    *(v8u*)(Or + q * 8) = o;
  }
}

// ---------------------------------------------------------------------------
extern "C" void kernel_launch(void* const* d_in, const int* in_sizes, int n_in,
                              void* d_out, int out_size, void* d_ws, size_t ws_size,
                              hipStream_t stream) {
  const float* X     = (const float*)d_in[0];  // [4,2048,768] f32
  const float* Wqkv  = (const float*)d_in[1];  // [2304,768]   f32
  const float* Wproj = (const float*)d_in[2];  // [768,768]    f32
  float* out = (float*)d_out;                  // [4,2048,768] f32

  const size_t SZ_QK = (size_t)8192 * 1536 * 2;       // 25.2 MB
  const size_t SZ_VT = (size_t)3072 * 2048 * 2;       // 12.6 MB
  const size_t SZ_SC = (size_t)12 * 136 * 16384 * 2;  // 53.5 MB
  const size_t SZ_AO = (size_t)8192 * 768 * 2;        // 12.6 MB
  const size_t SZ_WQ = (size_t)2304 * 768 * 2;        //  3.5 MB

  char* ws = (char*)d_ws;
  unsigned short* QKb = (unsigned short*)ws;
  unsigned short* Ppb = QKb;  // alias: QK dead after scv8; Pp == SZ_QK
  unsigned short* VTb = (unsigned short*)(ws + SZ_QK);
  unsigned short* Scb = (unsigned short*)(ws + SZ_QK + SZ_VT);
  unsigned short* AOb = (unsigned short*)(ws + SZ_QK + SZ_VT + SZ_SC);
  unsigned short* Xb  = AOb;  // alias: Xb dead after scv8; AO written by combine (later)
  unsigned short* Wqb = (unsigned short*)(ws + SZ_QK + SZ_VT + SZ_SC + SZ_AO);
  unsigned short* Wpb = (unsigned short*)(ws + SZ_QK + SZ_VT + SZ_SC + SZ_AO + SZ_WQ);

  dim3 blk(256, 1, 1);
  // 0) one-time f32 -> f16 conversions (single launch)
  cvt3_kernel<<<dim3(4224, 1, 1), blk, 0, stream>>>(X, Wqkv, Wproj, Xb, Wqb, Wpb);
  // 1) Q,K projection, 256^2 8-phase schedule, one round
  qkv8_kernel<<<dim3(6, 32, 1), dim3(512, 1, 1), 0, stream>>>(Xb, Wqb, QKb);
  // 2) score tiles + V projection, 256^2 8-phase, ONE dispatch (V-first LPT)
  scv8_kernel<<<dim3(528, 1, 1), dim3(512, 1, 1), 0, stream>>>(QKb, Xb, Wqb, Scb, VTb);
  softmax_kernel<<<dim3(512, 12, 1), blk, 0, stream>>>(Scb);
  gemm_pv_kernel<<<dim3(64, 12, 1), blk, 0, stream>>>(Scb, VTb, Ppb);
  pv_combine_kernel<<<dim3(32, 12, 1), blk, 0, stream>>>(Ppb, AOb);
  // 3) output projection, f32 store
  gemm_proj_kernel<<<dim3(6, 64, 1), blk, 0, stream>>>(AOb, Wpb, out);
}

// Round 5
// 223.550 us; speedup vs baseline: 1.1880x; 1.0898x over previous
//
#include <hip/hip_runtime.h>

using v8h = __attribute__((ext_vector_type(8))) _Float16;       // 8 f16 MFMA frag
using v4f = __attribute__((ext_vector_type(4))) float;          // MFMA acc
using v4u = __attribute__((ext_vector_type(4))) unsigned short; // 8B packed
using v8u = __attribute__((ext_vector_type(8))) unsigned short; // 16B copy

// fp32 <-> fp16
__device__ __forceinline__ unsigned short f2h(float x) {
  _Float16 h = (_Float16)x;
  return __builtin_bit_cast(unsigned short, h);
}
__device__ __forceinline__ float h2f(unsigned short u) {
  return (float)__builtin_bit_cast(_Float16, u);
}

// async global -> LDS, 16 bytes per lane (global_load_lds_dwordx4)
__device__ __forceinline__ void gl_lds16(const unsigned short* g, unsigned short* l) {
  __builtin_amdgcn_global_load_lds(
      (const __attribute__((address_space(1))) unsigned int*)g,
      (__attribute__((address_space(3))) unsigned int*)l, 16, 0, 0);
}

// ---------------------------------------------------------------------------
// All three f32 -> f16 conversions in ONE launch. Grid 4224 x 256, exact
// multiples (3072 / 864 / 288 blocks), 8 elems/thread, no guards needed.
// ---------------------------------------------------------------------------
__global__ void cvt3_kernel(const float* __restrict__ X,
                            const float* __restrict__ Wq,
                            const float* __restrict__ Wp,
                            unsigned short* __restrict__ Xb,
                            unsigned short* __restrict__ Wqb,
                            unsigned short* __restrict__ Wpb) {
  const int blk = (int)blockIdx.x;
  const float* src;
  unsigned short* dst;
  int i;
  if (blk < 3072)      { src = X;  dst = Xb;  i = blk * 256 + threadIdx.x; }
  else if (blk < 3936) { src = Wq; dst = Wqb; i = (blk - 3072) * 256 + threadIdx.x; }
  else                 { src = Wp; dst = Wpb; i = (blk - 3936) * 256 + threadIdx.x; }
  const float* p = src + (size_t)i * 8;
  float4 a = *(const float4*)p;
  float4 b = *(const float4*)(p + 4);
  v8u o = {f2h(a.x), f2h(a.y), f2h(a.z), f2h(a.w),
           f2h(b.x), f2h(b.y), f2h(b.z), f2h(b.w)};
  *(v8u*)(dst + (size_t)i * 8) = o;
}

// ---------------------------------------------------------------------------
// QK projection: 256x256 tile, BK=64, 512 thr = 8 waves (2M x 4N),
// 8-phase counted-vmcnt schedule + XOR swizzle + setprio.
// A[8192][768] f16, Bw rows 0..1535 (Q,K out-features).
// Grid (6, 32) = 192 blocks -> ONE round at 1 block/CU (128KB LDS).
// ---------------------------------------------------------------------------
__global__ __launch_bounds__(512, 2)
void qkv8_kernel(const unsigned short* __restrict__ A,
                 const unsigned short* __restrict__ Bw,
                 unsigned short* __restrict__ QK) {
  __shared__ unsigned short sm[65536];  // 128 KB
  const int t    = (int)threadIdx.x;
  const int ln   = t & 63;
  const int wv   = t >> 6;
  const int quad = ln >> 4;
  const int L    = ln & 15;
  const int wm   = wv >> 2;   // 0..1 -> 128-row half of the 256-row tile
  const int wn   = wv & 3;    // 0..3 -> 64-col stripe
  const long m0  = (long)blockIdx.y * 256;
  const long n0  = (long)blockIdx.x * 256;

  const int srow = t >> 3;                        // 0..63
  const int scol = ((t & 7) ^ (srow & 7)) * 8;    // shorts
  const unsigned short* Ath = A + (m0 + srow) * 768 + scol;
  const unsigned short* Bth = Bw + (n0 + srow) * 768 + scol;
  unsigned short* lth = &sm[t * 8];

  const int l7   = L & 7;
  const int sl0  = ((0 + quad) ^ l7) * 8;   // ks=0, shorts
  const int sl1  = ((4 + quad) ^ l7) * 8;   // ks=1
  const int arow = (wm * 128 + L) * 64;     // shorts
  const int brow = (wn * 64 + L) * 64;      // shorts

  v4f acc[8][4];
#pragma unroll
  for (int i = 0; i < 8; i++)
#pragma unroll
    for (int j = 0; j < 4; j++) acc[i][j] = (v4f){0.f, 0.f, 0.f, 0.f};

  auto stA = [&](int tile, int h) {
    if (tile >= 12) return;
    const unsigned short* g = Ath + (h * 128) * 768 + tile * 64;
    unsigned short* l = lth + (tile & 1) * 32768 + h * 8192;
    gl_lds16(g, l);
    gl_lds16(g + 64 * 768, l + 4096);
  };
  auto stB = [&](int tile, int h) {
    if (tile >= 12) return;
    const unsigned short* g = Bth + (h * 128) * 768 + tile * 64;
    unsigned short* l = lth + (tile & 1) * 32768 + 16384 + h * 8192;
    gl_lds16(g, l);
    gl_lds16(g + 64 * 768, l + 4096);
  };

  stB(0, 0); stB(0, 1); stA(0, 0); stA(0, 1);
  stB(1, 0); stB(1, 1); stA(1, 0);
  asm volatile("s_waitcnt vmcnt(6)" ::: "memory");
  __builtin_amdgcn_s_barrier();
  __builtin_amdgcn_sched_barrier(0);

#pragma unroll 2
  for (int kt = 0; kt < 12; ++kt) {
    const unsigned short* sA = &sm[(kt & 1) * 32768];
    const unsigned short* sB = sA + 16384;
    v8h af[4][2], b0[2][2], b1[2][2];

    // ---- phase 1: (mq0, nh0)
#pragma unroll
    for (int i = 0; i < 4; i++) {
      af[i][0] = *(const v8h*)&sA[arow + i * 1024 + sl0];
      af[i][1] = *(const v8h*)&sA[arow + i * 1024 + sl1];
    }
#pragma unroll
    for (int j = 0; j < 2; j++) {
      b0[j][0] = *(const v8h*)&sB[brow + j * 1024 + sl0];
      b0[j][1] = *(const v8h*)&sB[brow + j * 1024 + sl1];
    }
    stA(kt + 1, 1);
    __builtin_amdgcn_s_barrier();
    asm volatile("s_waitcnt lgkmcnt(0)" ::: "memory");
    __builtin_amdgcn_sched_barrier(0);
    __builtin_amdgcn_s_setprio(1);
#pragma unroll
    for (int i = 0; i < 4; i++)
#pragma unroll
      for (int j = 0; j < 2; j++) {
        acc[i][j] = __builtin_amdgcn_mfma_f32_16x16x32_f16(af[i][0], b0[j][0], acc[i][j], 0, 0, 0);
        acc[i][j] = __builtin_amdgcn_mfma_f32_16x16x32_f16(af[i][1], b0[j][1], acc[i][j], 0, 0, 0);
      }
    __builtin_amdgcn_s_setprio(0);
    __builtin_amdgcn_s_barrier();
    __builtin_amdgcn_sched_barrier(0);

    // ---- phase 2: (mq0, nh1)
#pragma unroll
    for (int j = 0; j < 2; j++) {
      b1[j][0] = *(const v8h*)&sB[brow + 2048 + j * 1024 + sl0];
      b1[j][1] = *(const v8h*)&sB[brow + 2048 + j * 1024 + sl1];
    }
    __builtin_amdgcn_s_barrier();
    asm volatile("s_waitcnt lgkmcnt(0)" ::: "memory");
    __builtin_amdgcn_sched_barrier(0);
    __builtin_amdgcn_s_setprio(1);
#pragma unroll
    for (int i = 0; i < 4; i++)
#pragma unroll
      for (int j = 0; j < 2; j++) {
        acc[i][2 + j] = __builtin_amdgcn_mfma_f32_16x16x32_f16(af[i][0], b1[j][0], acc[i][2 + j], 0, 0, 0);
        acc[i][2 + j] = __builtin_amdgcn_mfma_f32_16x16x32_f16(af[i][1], b1[j][1], acc[i][2 + j], 0, 0, 0);
      }
    __builtin_amdgcn_s_setprio(0);
    __builtin_amdgcn_s_barrier();
    __builtin_amdgcn_sched_barrier(0);

    // ---- phase 3: (mq1, nh1)
#pragma unroll
    for (int i = 0; i < 4; i++) {
      af[i][0] = *(const v8h*)&sA[arow + 4096 + i * 1024 + sl0];
      af[i][1] = *(const v8h*)&sA[arow + 4096 + i * 1024 + sl1];
    }
    stB(kt + 2, 0);
    __builtin_amdgcn_s_barrier();
    asm volatile("s_waitcnt lgkmcnt(0)" ::: "memory");
    __builtin_amdgcn_sched_barrier(0);
    __builtin_amdgcn_s_setprio(1);
#pragma unroll
    for (int i = 0; i < 4; i++)
#pragma unroll
      for (int j = 0; j < 2; j++) {
        acc[4 + i][2 + j] = __builtin_amdgcn_mfma_f32_16x16x32_f16(af[i][0], b1[j][0], acc[4 + i][2 + j], 0, 0, 0);
        acc[4 + i][2 + j] = __builtin_amdgcn_mfma_f32_16x16x32_f16(af[i][1], b1[j][1], acc[4 + i][2 + j], 0, 0, 0);
      }
    __builtin_amdgcn_s_setprio(0);
    __builtin_amdgcn_s_barrier();
    __builtin_amdgcn_sched_barrier(0);

    // ---- phase 4: (mq1, nh0)
    stB(kt + 2, 1);
    stA(kt + 2, 0);
    __builtin_amdgcn_s_barrier();
    __builtin_amdgcn_sched_barrier(0);
    __builtin_amdgcn_s_setprio(1);
#pragma unroll
    for (int i = 0; i < 4; i++)
#pragma unroll
      for (int j = 0; j < 2; j++) {
        acc[4 + i][j] = __builtin_amdgcn_mfma_f32_16x16x32_f16(af[i][0], b0[j][0], acc[4 + i][j], 0, 0, 0);
        acc[4 + i][j] = __builtin_amdgcn_mfma_f32_16x16x32_f16(af[i][1], b0[j][1], acc[4 + i][j], 0, 0, 0);
      }
    __builtin_amdgcn_s_setprio(0);
    if (kt + 2 < 12)      { asm volatile("s_waitcnt vmcnt(6)" ::: "memory"); }
    else if (kt + 1 < 12) { asm volatile("s_waitcnt vmcnt(0)" ::: "memory"); }
    __builtin_amdgcn_s_barrier();
    __builtin_amdgcn_sched_barrier(0);
  }

#pragma unroll
  for (int mi = 0; mi < 8; mi++) {
    const long row = m0 + wm * 128 + (mi >> 2) * 64 + (mi & 3) * 16 + quad * 4;
#pragma unroll
    for (int nj = 0; nj < 4; nj++) {
      const long col = n0 + wn * 64 + nj * 16 + L;
#pragma unroll
      for (int r = 0; r < 4; r++)
        QK[(row + r) * 1536 + col] = f2h(acc[mi][nj][r]);
    }
  }
}

// ---------------------------------------------------------------------------
// COMBINED score + V-projection, 256^2 tiles, 8-phase schedule. Grid (528, 1):
//   x < 96  : V-projection -> VT transposed. NT=12.
//   x >= 96 : score 256-tile -> four 128^2 sub-tiles into packed lower-tri Sc
//             (raw unscaled scores). NT=4.
// ---------------------------------------------------------------------------
__global__ __launch_bounds__(512, 2)
void scv8_kernel(const unsigned short* __restrict__ QK,
                 const unsigned short* __restrict__ Xb,
                 const unsigned short* __restrict__ Wq,
                 unsigned short* __restrict__ Sc,
                 unsigned short* __restrict__ VT) {
  __shared__ unsigned short sm[65536];  // 128 KB
  const int t    = (int)threadIdx.x;
  const int ln   = t & 63;
  const int wv   = t >> 6;
  const int quad = ln >> 4;
  const int L    = ln & 15;
  const int wm   = wv >> 2;
  const int wn   = wv & 3;

  const int x = (int)blockIdx.x;
  const bool isV = (x < 96);
  int NT, Ihi = 0, Jhi = 0, bh = 0, mt = 0, nt = 0;
  const unsigned short* Abase;
  const unsigned short* Bbase;
  long astr, bstr;

  if (isV) {
    mt = x & 31;
    nt = x >> 5;
    Abase = Xb + (long)mt * 256 * 768;
    Bbase = Wq + (long)(1536 + nt * 256) * 768;
    astr = 768; bstr = 768; NT = 12;
  } else {
    int s = x - 96;
    bh = s / 36;
    int slot = s % 36;
    while (slot >= Ihi + 1) { slot -= Ihi + 1; Ihi++; }
    Jhi = slot;
    const int b = bh / 3, h = bh % 3;
    Abase = QK + ((long)b * 2048 + Ihi * 256) * 1536 + h * 256;
    Bbase = QK + ((long)b * 2048 + Jhi * 256) * 1536 + 768 + h * 256;
    astr = 1536; bstr = 1536; NT = 4;
  }

  const int srow = t >> 3;
  const int scol = ((t & 7) ^ (srow & 7)) * 8;
  const unsigned short* Ath = Abase + (long)srow * astr + scol;
  const unsigned short* Bth = Bbase + (long)srow * bstr + scol;
  unsigned short* lth = &sm[t * 8];

  const int l7   = L & 7;
  const int sl0  = ((0 + quad) ^ l7) * 8;
  const int sl1  = ((4 + quad) ^ l7) * 8;
  const int arow = (wm * 128 + L) * 64;
  const int brow = (wn * 64 + L) * 64;

  v4f acc[8][4];
#pragma unroll
  for (int i = 0; i < 8; i++)
#pragma unroll
    for (int j = 0; j < 4; j++) acc[i][j] = (v4f){0.f, 0.f, 0.f, 0.f};

  auto stA = [&](int tile, int h) {
    if (tile >= NT) return;
    const unsigned short* g = Ath + (long)(h * 128) * astr + tile * 64;
    unsigned short* l = lth + (tile & 1) * 32768 + h * 8192;
    gl_lds16(g, l);
    gl_lds16(g + 64 * astr, l + 4096);
  };
  auto stB = [&](int tile, int h) {
    if (tile >= NT) return;
    const unsigned short* g = Bth + (long)(h * 128) * bstr + tile * 64;
    unsigned short* l = lth + (tile & 1) * 32768 + 16384 + h * 8192;
    gl_lds16(g, l);
    gl_lds16(g + 64 * bstr, l + 4096);
  };

  stB(0, 0); stB(0, 1); stA(0, 0); stA(0, 1);
  stB(1, 0); stB(1, 1); stA(1, 0);
  asm volatile("s_waitcnt vmcnt(6)" ::: "memory");
  __builtin_amdgcn_s_barrier();
  __builtin_amdgcn_sched_barrier(0);

#pragma unroll 2
  for (int kt = 0; kt < NT; ++kt) {
    const unsigned short* sA = &sm[(kt & 1) * 32768];
    const unsigned short* sB = sA + 16384;
    v8h af[4][2], b0[2][2], b1[2][2];

#pragma unroll
    for (int i = 0; i < 4; i++) {
      af[i][0] = *(const v8h*)&sA[arow + i * 1024 + sl0];
      af[i][1] = *(const v8h*)&sA[arow + i * 1024 + sl1];
    }
#pragma unroll
    for (int j = 0; j < 2; j++) {
      b0[j][0] = *(const v8h*)&sB[brow + j * 1024 + sl0];
      b0[j][1] = *(const v8h*)&sB[brow + j * 1024 + sl1];
    }
    stA(kt + 1, 1);
    __builtin_amdgcn_s_barrier();
    asm volatile("s_waitcnt lgkmcnt(0)" ::: "memory");
    __builtin_amdgcn_sched_barrier(0);
    __builtin_amdgcn_s_setprio(1);
#pragma unroll
    for (int i = 0; i < 4; i++)
#pragma unroll
      for (int j = 0; j < 2; j++) {
        acc[i][j] = __builtin_amdgcn_mfma_f32_16x16x32_f16(af[i][0], b0[j][0], acc[i][j], 0, 0, 0);
        acc[i][j] = __builtin_amdgcn_mfma_f32_16x16x32_f16(af[i][1], b0[j][1], acc[i][j], 0, 0, 0);
      }
    __builtin_amdgcn_s_setprio(0);
    __builtin_amdgcn_s_barrier();
    __builtin_amdgcn_sched_barrier(0);

#pragma unroll
    for (int j = 0; j < 2; j++) {
      b1[j][0] = *(const v8h*)&sB[brow + 2048 + j * 1024 + sl0];
      b1[j][1] = *(const v8h*)&sB[brow + 2048 + j * 1024 + sl1];
    }
    __builtin_amdgcn_s_barrier();
    asm volatile("s_waitcnt lgkmcnt(0)" ::: "memory");
    __builtin_amdgcn_sched_barrier(0);
    __builtin_amdgcn_s_setprio(1);
#pragma unroll
    for (int i = 0; i < 4; i++)
#pragma unroll
      for (int j = 0; j < 2; j++) {
        acc[i][2 + j] = __builtin_amdgcn_mfma_f32_16x16x32_f16(af[i][0], b1[j][0], acc[i][2 + j], 0, 0, 0);
        acc[i][2 + j] = __builtin_amdgcn_mfma_f32_16x16x32_f16(af[i][1], b1[j][1], acc[i][2 + j], 0, 0, 0);
      }
    __builtin_amdgcn_s_setprio(0);
    __builtin_amdgcn_s_barrier();
    __builtin_amdgcn_sched_barrier(0);

#pragma unroll
    for (int i = 0; i < 4; i++) {
      af[i][0] = *(const v8h*)&sA[arow + 4096 + i * 1024 + sl0];
      af[i][1] = *(const v8h*)&sA[arow + 4096 + i * 1024 + sl1];
    }
    stB(kt + 2, 0);
    __builtin_amdgcn_s_barrier();
    asm volatile("s_waitcnt lgkmcnt(0)" ::: "memory");
    __builtin_amdgcn_sched_barrier(0);
    __builtin_amdgcn_s_setprio(1);
#pragma unroll
    for (int i = 0; i < 4; i++)
#pragma unroll
      for (int j = 0; j < 2; j++) {
        acc[4 + i][2 + j] = __builtin_amdgcn_mfma_f32_16x16x32_f16(af[i][0], b1[j][0], acc[4 + i][2 + j], 0, 0, 0);
        acc[4 + i][2 + j] = __builtin_amdgcn_mfma_f32_16x16x32_f16(af[i][1], b1[j][1], acc[4 + i][2 + j], 0, 0, 0);
      }
    __builtin_amdgcn_s_setprio(0);
    __builtin_amdgcn_s_barrier();
    __builtin_amdgcn_sched_barrier(0);

    stB(kt + 2, 1);
    stA(kt + 2, 0);
    __builtin_amdgcn_s_barrier();
    __builtin_amdgcn_sched_barrier(0);
    __builtin_amdgcn_s_setprio(1);
#pragma unroll
    for (int i = 0; i < 4; i++)
#pragma unroll
      for (int j = 0; j < 2; j++) {
        acc[4 + i][j] = __builtin_amdgcn_mfma_f32_16x16x32_f16(af[i][0], b0[j][0], acc[4 + i][j], 0, 0, 0);
        acc[4 + i][j] = __builtin_amdgcn_mfma_f32_16x16x32_f16(af[i][1], b0[j][1], acc[4 + i][j], 0, 0, 0);
      }
    __builtin_amdgcn_s_setprio(0);
    if (kt + 2 < NT)      { asm volatile("s_waitcnt vmcnt(6)" ::: "memory"); }
    else if (kt + 1 < NT) { asm volatile("s_waitcnt vmcnt(0)" ::: "memory"); }
    __builtin_amdgcn_s_barrier();
    __builtin_amdgcn_sched_barrier(0);
  }

  if (isV) {
#pragma unroll
    for (int mi = 0; mi < 8; mi++) {
      const long token = (long)mt * 256 + wm * 128 + (mi >> 2) * 64 + (mi & 3) * 16 + quad * 4;
      const int b  = (int)(token >> 11);
      const int tk = (int)(token & 2047);
#pragma unroll
      for (int nj = 0; nj < 4; nj++) {
        const int colp = nt * 256 + wn * 64 + nj * 16 + L;
        const int h    = colp >> 8;
        const int d    = colp & 255;
        v4u val = {f2h(acc[mi][nj][0]), f2h(acc[mi][nj][1]),
                   f2h(acc[mi][nj][2]), f2h(acc[mi][nj][3])};
        *(v4u*)(&VT[((long)(b * 3 + h) * 256 + d) * 2048 + tk]) = val;
      }
    }
  } else {
    const int di = wm;
    const int dj = wn >> 1;
    const int i128 = 2 * Ihi + di;
    const int j128 = 2 * Jhi + dj;
    if (j128 <= i128) {
      unsigned short* Sb = Sc + ((long)bh * 136 + (long)i128 * (i128 + 1) / 2 + j128) * 16384;
#pragma unroll
      for (int mi = 0; mi < 8; mi++) {
        const int subrow = (mi >> 2) * 64 + (mi & 3) * 16 + quad * 4;
#pragma unroll
        for (int nj = 0; nj < 4; nj++) {
          const int subcol = (wn & 1) * 64 + nj * 16 + L;
#pragma unroll
          for (int r = 0; r < 4; r++)
            Sb[(subrow + r) * 128 + subcol] = f2h(acc[mi][nj][r]);
        }
      }
    }
  }
}

// ---------------------------------------------------------------------------
// FUSED online-softmax + PV + store (flash-style, reads RAW scores from Sc).
// Grid (16, 12), 512 thr = 8 waves. Block = (pair p = x>>1, nh = x&1, bh).
// Processes Q-tiles i = p and 15-p sequentially: steps (p+1)+(16-p) = 17.
// Per wave: 16 Q-rows (rows wv*16+L for P; acc rows wv*16+quad*4+r).
// Per step j: prefetch S(j+1)->regs, stage V(j+1)->swizzled LDS (dbuf),
// online softmax in-register (quad-shuffle row reduce, alpha via LDS
// transpose), P.V MFMA from LDS. O divided by l and stored f16 to AO.
// ---------------------------------------------------------------------------
__global__ __launch_bounds__(512, 1)
void pvf_kernel(const unsigned short* __restrict__ Sc,
                const unsigned short* __restrict__ VT,
                unsigned short* __restrict__ AO) {
  __shared__ unsigned short sm[36864];  // buf0 16384, buf1 16384, scratch 4096
  __shared__ float fbuf[128];           // per-wave 16-float alpha/inv slices

  const int t    = (int)threadIdx.x;
  const int ln   = t & 63;
  const int wv   = t >> 6;     // 0..7
  const int quad = ln >> 4;
  const int L    = ln & 15;

  const int p  = (int)blockIdx.x >> 1;
  const int nh = (int)blockIdx.x & 1;
  const int bh = (int)blockIdx.y;
  const int b  = bh / 3, h = bh % 3;

  const unsigned short* VTb = VT + ((long)(bh * 256 + nh * 128)) * 2048;
  const int rloc = wv * 16 + L;  // local Q-row this lane owns for softmax

  // stage V(jj) tile (128 d x 128 kv f16, 32KB) into LDS with XOR swizzle:
  // phys slot s of d-row holds logical kv-slot s^(d&7); source pre-swizzled.
  auto stageV = [&](int jj, unsigned short* base) {
#pragma unroll
    for (int pp = 0; pp < 4; pp++) {
      const int sidx = pp * 512 + t;        // 0..2047
      const int d    = sidx >> 4;
      const int ph   = sidx & 15;
      gl_lds16(VTb + (long)d * 2048 + jj * 128 + ((ph ^ (d & 7)) * 8),
               base + sidx * 8);
    }
  };

  for (int sel = 0; sel < 2; ++sel) {
    const int i = sel ? (15 - p) : p;
    const long Sbase = ((long)bh * 136 + (long)i * (i + 1) / 2) * 16384;

    v4f acc[8];
#pragma unroll
    for (int n = 0; n < 8; n++) acc[n] = (v4f){0.f, 0.f, 0.f, 0.f};
    float m_run = -1e30f, l_run = 0.f;

    // prologue: issue S(0) and stage V(0) -> buf0
    v8u s_cur[4], s_nxt[4];
    {
      const unsigned short* Sp = Sc + Sbase + (long)rloc * 128;
#pragma unroll
      for (int ks = 0; ks < 4; ks++)
        s_cur[ks] = *(const v8u*)(Sp + ks * 32 + quad * 8);
      __builtin_amdgcn_sched_barrier(0);
      stageV(0, &sm[0]);
      __builtin_amdgcn_sched_barrier(0);
    }

    for (int j = 0; j <= i; ++j) {
      const int jn = (j < i) ? (j + 1) : i;  // clamped prefetch (uniform count)
      const bool clamped = (j == i);
      // issue S(jn) -> regs
      {
        const unsigned short* Sp = Sc + Sbase + (long)jn * 16384 + (long)rloc * 128;
#pragma unroll
        for (int ks = 0; ks < 4; ks++)
          s_nxt[ks] = *(const v8u*)(Sp + ks * 32 + quad * 8);
      }
      __builtin_amdgcn_sched_barrier(0);
      // stage V(jn) -> buf (jn&1); clamped -> scratch (keeps vmcnt uniform,
      // avoids racing the next i's buf0 stage)
      if (clamped) {
#pragma unroll
        for (int pp = 0; pp < 4; pp++) {
          const int sidx = pp * 512 + t;
          const int d    = sidx >> 4;
          const int ph   = sidx & 15;
          gl_lds16(VTb + (long)d * 2048 + jn * 128 + ((ph ^ (d & 7)) * 8),
                   &sm[32768 + t * 8]);
        }
      } else {
        stageV(jn, &sm[(jn & 1) * 16384]);
      }
      __builtin_amdgcn_sched_barrier(0);

      // ---- online softmax on s_cur (raw scores * 1/16) ----
      float pv[4][8];
      float mx = -1e30f;
      if (j == i) {  // diagonal tile: causal mask c <= r (local)
#pragma unroll
        for (int ks = 0; ks < 4; ks++)
#pragma unroll
          for (int e = 0; e < 8; e++) {
            const bool valid = (ks * 32 + quad * 8 + e) <= rloc;
            const float f = valid ? h2f(s_cur[ks][e]) * 0.0625f : -1e30f;
            pv[ks][e] = f;
            mx = fmaxf(mx, f);
          }
      } else {
#pragma unroll
        for (int ks = 0; ks < 4; ks++)
#pragma unroll
          for (int e = 0; e < 8; e++) {
            const float f = h2f(s_cur[ks][e]) * 0.0625f;
            pv[ks][e] = f;
            mx = fmaxf(mx, f);
          }
      }
      mx = fmaxf(mx, __shfl_xor(mx, 16));
      mx = fmaxf(mx, __shfl_xor(mx, 32));
      const float m_new = fmaxf(m_run, mx);
      const float alpha = __expf(m_run - m_new);
      m_run = m_new;

      float sum = 0.f;
      v8h pa[4];
#pragma unroll
      for (int ks = 0; ks < 4; ks++) {
        v8h ph16;
#pragma unroll
        for (int e = 0; e < 8; e++) {
          const float pe = __expf(pv[ks][e] - m_new);  // masked -> exp(-huge)=0
          sum += pe;
          ph16[e] = (_Float16)pe;
        }
        pa[ks] = ph16;
      }
      sum += __shfl_xor(sum, 16);
      sum += __shfl_xor(sum, 32);
      l_run = l_run * alpha + sum;

      // alpha transpose: P-row layout (row=L) -> acc-row layout (row=quad*4+r)
      if (quad == 0) fbuf[wv * 16 + L] = alpha;
      asm volatile("s_waitcnt lgkmcnt(0)" ::: "memory");
      __builtin_amdgcn_sched_barrier(0);
      const float a0 = fbuf[wv * 16 + quad * 4 + 0];
      const float a1 = fbuf[wv * 16 + quad * 4 + 1];
      const float a2 = fbuf[wv * 16 + quad * 4 + 2];
      const float a3 = fbuf[wv * 16 + quad * 4 + 3];
#pragma unroll
      for (int n = 0; n < 8; n++) {
        acc[n][0] *= a0; acc[n][1] *= a1; acc[n][2] *= a2; acc[n][3] *= a3;
      }

      // V(j) staged (8 newest = S(jn)4 + V(jn)4 stay in flight)
      asm volatile("s_waitcnt vmcnt(8)" ::: "memory");
      __builtin_amdgcn_s_barrier();
      __builtin_amdgcn_sched_barrier(0);

      // ---- PV MFMA from swizzled LDS ----
      const unsigned short* vb = &sm[(j & 1) * 16384];
      const int dx = L & 7;  // (nfc*16+L)&7 == L&7
#pragma unroll
      for (int nfc = 0; nfc < 8; nfc++) {
        const int dbase = (nfc * 16 + L) * 128;
        v8h v0 = *(const v8h*)&vb[dbase + ((0 + quad) ^ dx) * 8];
        v8h v1 = *(const v8h*)&vb[dbase + ((4 + quad) ^ dx) * 8];
        v8h v2 = *(const v8h*)&vb[dbase + ((8 + quad) ^ dx) * 8];
        v8h v3 = *(const v8h*)&vb[dbase + ((12 + quad) ^ dx) * 8];
        acc[nfc] = __builtin_amdgcn_mfma_f32_16x16x32_f16(pa[0], v0, acc[nfc], 0, 0, 0);
        acc[nfc] = __builtin_amdgcn_mfma_f32_16x16x32_f16(pa[1], v1, acc[nfc], 0, 0, 0);
        acc[nfc] = __builtin_amdgcn_mfma_f32_16x16x32_f16(pa[2], v2, acc[nfc], 0, 0, 0);
        acc[nfc] = __builtin_amdgcn_mfma_f32_16x16x32_f16(pa[3], v3, acc[nfc], 0, 0, 0);
      }
      __builtin_amdgcn_s_barrier();
      __builtin_amdgcn_sched_barrier(0);

#pragma unroll
      for (int ks = 0; ks < 4; ks++) s_cur[ks] = s_nxt[ks];
    }

    // finalize: divide by l (transpose inv like alpha) and store f16 to AO
    const float inv = 1.0f / l_run;
    if (quad == 0) fbuf[wv * 16 + L] = inv;
    asm volatile("s_waitcnt lgkmcnt(0)" ::: "memory");
    __builtin_amdgcn_sched_barrier(0);
    const float i0 = fbuf[wv * 16 + quad * 4 + 0];
    const float i1 = fbuf[wv * 16 + quad * 4 + 1];
    const float i2 = fbuf[wv * 16 + quad * 4 + 2];
    const float i3 = fbuf[wv * 16 + quad * 4 + 3];

    unsigned short* Ob = AO + ((long)b * 2048 + (long)i * 128 + wv * 16 + quad * 4) * 768
                            + h * 256 + nh * 128 + L;
#pragma unroll
    for (int n = 0; n < 8; n++) {
      Ob[0 * 768 + n * 16] = f2h(acc[n][0] * i0);
      Ob[1 * 768 + n * 16] = f2h(acc[n][1] * i1);
      Ob[2 * 768 + n * 16] = f2h(acc[n][2] * i2);
      Ob[3 * 768 + n * 16] = f2h(acc[n][3] * i3);
    }
    __builtin_amdgcn_s_barrier();  // all reads of V bufs done before next i
  }
}

// ---------------------------------------------------------------------------
// f16 GEMM, m97 recipe (output projection): C[m,n] = sum_k A[m,k]*Bw[n,k],
// 128x128 tile, BK=32, f32 store.
// ---------------------------------------------------------------------------
__global__ __launch_bounds__(256, 2)
void gemm_proj_kernel(const unsigned short* __restrict__ A,
                      const unsigned short* __restrict__ Bw,
                      float* __restrict__ C) {
  __shared__ unsigned short As[4096];
  __shared__ unsigned short Bs[4096];

  const int t    = threadIdx.x;
  const int ln   = t & 63;
  const int wv   = t >> 6;
  const int quad = ln >> 4;
  const int L    = ln & 15;
  const int wm   = (wv >> 1) * 64;
  const int wn   = (wv & 1) * 64;
  const long m0  = (long)blockIdx.y * 128;
  const long n0  = (long)blockIdx.x * 128;

  v4f acc[4][4];
#pragma unroll
  for (int i = 0; i < 4; i++)
#pragma unroll
    for (int j = 0; j < 4; j++) acc[i][j] = (v4f){0.f, 0.f, 0.f, 0.f};

  const int ar = t >> 2;
  const int ac = (t & 3) * 8;
  const unsigned short* Ag = A + (m0 + ar) * 768 + ac;
  const unsigned short* Bg = Bw + (n0 + ar) * 768 + ac;
  unsigned short* la = &As[t * 8];
  unsigned short* lb = &Bs[t * 8];
  const long rowskip = 64L * 768;

  for (int k0 = 0; k0 < 768; k0 += 32) {
    gl_lds16(Ag + k0, la);
    gl_lds16(Ag + rowskip + k0, la + 2048);
    gl_lds16(Bg + k0, lb);
    gl_lds16(Bg + rowskip + k0, lb + 2048);
    __syncthreads();

    v8h af[4], bfr[4];
#pragma unroll
    for (int i = 0; i < 4; i++)
      af[i] = *(const v8h*)(&As[(wm + i * 16 + L) * 32 + quad * 8]);
#pragma unroll
    for (int j = 0; j < 4; j++)
      bfr[j] = *(const v8h*)(&Bs[(wn + j * 16 + L) * 32 + quad * 8]);
#pragma unroll
    for (int i = 0; i < 4; i++)
#pragma unroll
      for (int j = 0; j < 4; j++)
        acc[i][j] = __builtin_amdgcn_mfma_f32_16x16x32_f16(af[i], bfr[j], acc[i][j], 0, 0, 0);
    __syncthreads();
  }

#pragma unroll
  for (int i = 0; i < 4; i++)
#pragma unroll
    for (int j = 0; j < 4; j++)
#pragma unroll
      for (int r = 0; r < 4; r++) {
        long row = m0 + wm + i * 16 + quad * 4 + r;
        long col = n0 + wn + j * 16 + L;
        C[row * 768 + col] = acc[i][j][r];
      }
}

// ---------------------------------------------------------------------------
extern "C" void kernel_launch(void* const* d_in, const int* in_sizes, int n_in,
                              void* d_out, int out_size, void* d_ws, size_t ws_size,
                              hipStream_t stream) {
  const float* X     = (const float*)d_in[0];  // [4,2048,768] f32
  const float* Wqkv  = (const float*)d_in[1];  // [2304,768]   f32
  const float* Wproj = (const float*)d_in[2];  // [768,768]    f32
  float* out = (float*)d_out;                  // [4,2048,768] f32

  const size_t SZ_QK = (size_t)8192 * 1536 * 2;       // 25.2 MB
  const size_t SZ_VT = (size_t)3072 * 2048 * 2;       // 12.6 MB
  const size_t SZ_SC = (size_t)12 * 136 * 16384 * 2;  // 53.5 MB
  const size_t SZ_AO = (size_t)8192 * 768 * 2;        // 12.6 MB
  const size_t SZ_WQ = (size_t)2304 * 768 * 2;        //  3.5 MB

  char* ws = (char*)d_ws;
  unsigned short* QKb = (unsigned short*)ws;
  unsigned short* VTb = (unsigned short*)(ws + SZ_QK);
  unsigned short* Scb = (unsigned short*)(ws + SZ_QK + SZ_VT);
  unsigned short* AOb = (unsigned short*)(ws + SZ_QK + SZ_VT + SZ_SC);
  unsigned short* Xb  = AOb;  // alias: Xb dead after scv8; AO written by pvf (later)
  unsigned short* Wqb = (unsigned short*)(ws + SZ_QK + SZ_VT + SZ_SC + SZ_AO);
  unsigned short* Wpb = (unsigned short*)(ws + SZ_QK + SZ_VT + SZ_SC + SZ_AO + SZ_WQ);

  dim3 blk(256, 1, 1);
  // 0) one-time f32 -> f16 conversions (single launch)
  cvt3_kernel<<<dim3(4224, 1, 1), blk, 0, stream>>>(X, Wqkv, Wproj, Xb, Wqb, Wpb);
  // 1) Q,K projection, 256^2 8-phase schedule, one round
  qkv8_kernel<<<dim3(6, 32, 1), dim3(512, 1, 1), 0, stream>>>(Xb, Wqb, QKb);
  // 2) score tiles + V projection, 256^2 8-phase, ONE dispatch (V-first LPT)
  scv8_kernel<<<dim3(528, 1, 1), dim3(512, 1, 1), 0, stream>>>(QKb, Xb, Wqb, Scb, VTb);
  // 3) fused online-softmax + PV + store (replaces softmax/pv/combine)
  pvf_kernel<<<dim3(16, 12, 1), dim3(512, 1, 1), 0, stream>>>(Scb, VTb, AOb);
  // 4) output projection, f32 store
  gemm_proj_kernel<<<dim3(6, 64, 1), blk, 0, stream>>>(AOb, Wpb, out);
}